// Round 8
// baseline (530.772 us; speedup 1.0000x reference)
//
#include <hip/hip_runtime.h>
#include <cstdint>
#include <cstddef>

// SimpleGCN: h = x@W1+b1; 3x GCNConv(sym-norm adj w/ self loops); sigmoid(h@W2+b2)
// N=100000, d=128, E=1.6M.
// R8 = R7 + occupancy fix for fused kernels:
//   R7 counters: fusedA VGPR=88 -> histo blocks capped at 5 waves/SIMD (occupancy
//   17.8%), atomic throughput starved; fusedA ~= serial histo+gemm. Fix: GEMM
//   wave tile 32x128 -> 16x128 (acc[1][8]=32 VGPRs) + __launch_bounds__(256,7)
//   => ~73 VGPR cap, 7 waves/SIMD for histo blocks.
//   Also: memsets folded away (packed zero -> prep kernel; edata pad zeroing ->
//   scan3, which knows real-vs-padded counts).
// Numerics (replay-stability, from R6 failure): h state fp32 end-to-end; only
// messages/weights bf16. Deg via integer fixed-point atomic (order-exact).

typedef __attribute__((ext_vector_type(8))) short bf16x8;
typedef __attribute__((ext_vector_type(4))) float f32x4;

// ---------- bf16 helpers (packed dword: low 16 bits = element 0) ----------
__device__ __forceinline__ unsigned f2bf(float f) {      // RNE float->bf16 bits
    unsigned u = __float_as_uint(f);
    u += 0x7fffu + ((u >> 16) & 1u);
    return u >> 16;
}
__device__ __forceinline__ float bf_lo(unsigned p) { return __uint_as_float(p << 16); }
__device__ __forceinline__ float bf_hi(unsigned p) { return __uint_as_float(p & 0xffff0000u); }

// ---------- prep: bf16 W^T for all 4 layers + zero the packed histogram ----------
__global__ void prep_kernel(const float* __restrict__ W1, const float* __restrict__ Wg,
                            unsigned short* __restrict__ Wt,
                            unsigned long long* __restrict__ packed, int n) {
    int idx = blockIdx.x * blockDim.x + threadIdx.x;
    if (idx < 65536) {
        int l = idx >> 14, nn = (idx >> 7) & 127, k = idx & 127;
        const float* W = (l == 0) ? W1 : (Wg + (size_t)(l - 1) * 16384);
        Wt[idx] = (unsigned short)f2bf(W[k * 128 + nn]);
    }
    if (idx < n) packed[idx] = 0ull;
}

// ---------- GEMM body: 16x128 tile per wave (64 rows/block) ----------
// C[n x 128] = A[n x 128](fp32) @ W (+bias). No LDS/barriers; Wt L1-resident.
// A converted fp32->bf16 in-register. C bf16 (messages) or fp32 (h state).
template<bool C_BF16>
__device__ __forceinline__ void gemm_body(const float* __restrict__ A,
                                          const unsigned short* __restrict__ Wt,
                                          const float* __restrict__ bias,
                                          void* __restrict__ C, int n, int blk) {
    int tid = threadIdx.x;
    int wave = tid >> 6, lane = tid & 63;
    int lm = lane & 15, g = lane >> 4;
    int m_base = blk * 64 + wave * 16;

    f32x4 acc[8];
#pragma unroll
    for (int ct = 0; ct < 8; ++ct) acc[ct] = (f32x4){0.f, 0.f, 0.f, 0.f};

    size_t rowA = (size_t)min(m_base + lm, n - 1);

#pragma unroll
    for (int kc = 0; kc < 4; ++kc) {
        int k0 = kc * 32 + g * 8;
        bf16x8 a;
        {
            const float* p = A + rowA * 128 + k0;
            float f[8];
            *(float4*)&f[0] = *(const float4*)p;
            *(float4*)&f[4] = *(const float4*)(p + 4);
            short sv[8];
#pragma unroll
            for (int j = 0; j < 8; ++j) sv[j] = (short)f2bf(f[j]);
            a = *(bf16x8*)sv;
        }
#pragma unroll
        for (int ct = 0; ct < 8; ++ct) {
            bf16x8 b = *(const bf16x8*)(Wt + (ct * 16 + lm) * 128 + k0);
            acc[ct] = __builtin_amdgcn_mfma_f32_16x16x32_bf16(a, b, acc[ct], 0, 0, 0);
        }
    }

#pragma unroll
    for (int r = 0; r < 4; ++r) {
        int grow = m_base + g * 4 + r;
        if (grow < n) {
#pragma unroll
            for (int ct = 0; ct < 8; ++ct) {
                float v = acc[ct][r];
                if (bias) v += bias[ct * 16 + lm];
                if (C_BF16)
                    ((unsigned short*)C)[(size_t)grow * 128 + ct * 16 + lm] = (unsigned short)f2bf(v);
                else
                    ((float*)C)[(size_t)grow * 128 + ct * 16 + lm] = v;
            }
        }
    }
}

// ---------- scatter body (NO atomics): pos = row_ptr[c] + rank[e], 4 edges/thread ----------
// record = (src << 15) | (bf16(norm) & 0x7fff); norm > 0 so sign bit unused.
__device__ __forceinline__ void scatter_body(const int* __restrict__ row, const int* __restrict__ col,
                                             const float* __restrict__ ew, const float* __restrict__ dinv,
                                             const int* __restrict__ row_ptr,
                                             const unsigned short* __restrict__ rank,
                                             unsigned* __restrict__ edata, int E, int blk) {
    int e0 = (blk * 256 + threadIdx.x) * 4;
    if (e0 + 3 < E) {
        int4   r4 = *(const int4*)(row + e0);
        int4   c4 = *(const int4*)(col + e0);
        float4 w4 = *(const float4*)(ew + e0);
        ushort4 k4 = *(const ushort4*)(rank + e0);
        int   r[4] = {r4.x, r4.y, r4.z, r4.w};
        int   c[4] = {c4.x, c4.y, c4.z, c4.w};
        float w[4] = {w4.x, w4.y, w4.z, w4.w};
        unsigned short kk[4] = {k4.x, k4.y, k4.z, k4.w};
#pragma unroll
        for (int i = 0; i < 4; ++i) {
            float nrm = dinv[r[i]] * w[i] * dinv[c[i]];
            int pos = row_ptr[c[i]] + (int)kk[i];
            edata[pos] = ((unsigned)r[i] << 15) | (f2bf(nrm) & 0x7fffu);
        }
    } else {
        for (int e = e0; e < E; ++e) {
            int r = row[e], c = col[e];
            float nrm = dinv[r] * ew[e] * dinv[c];
            int pos = row_ptr[c] + (int)rank[e];
            edata[pos] = ((unsigned)r << 15) | (f2bf(nrm) & 0x7fffu);
        }
    }
}

// ---------- fused A: histo (1 u64 atomic/edge + rank) || gemm1 (x@W1+b1 -> fp32 h) ----------
// gemm blocks are b % K == 0 (b/K < nGemm); the rest are histo blocks.
__global__ __launch_bounds__(256, 7) void fusedA_kernel(const int* __restrict__ col,
                                                        const float* __restrict__ ewa,
                                                        unsigned long long* __restrict__ packed,
                                                        unsigned short* __restrict__ rank, int E,
                                                        const float* __restrict__ x,
                                                        const unsigned short* __restrict__ Wt0,
                                                        const float* __restrict__ b1,
                                                        float* __restrict__ hbuf, int n,
                                                        int nGemm, int K) {
    int b = blockIdx.x;
    int g = b / K, r = b - g * K;
    if (r == 0 && g < nGemm) {
        gemm_body<false>(x, Wt0, b1, hbuf, n, g);
    } else {
        int hb = b - min(g + (r > 0 ? 1 : 0), nGemm);
        int e = hb * 256 + threadIdx.x;
        if (e < E) {
            int c = col[e];
            unsigned long long v = (1ull << 40) |
                (unsigned long long)(unsigned)(ewa[e] * 16777216.0f);
            unsigned long long old = atomicAdd(&packed[c], v);
            rank[e] = (unsigned short)(old >> 40);
        }
    }
}

// ---------- fused E: scatter || gemm2 (hbuf@Wg0 -> tbuf bf16) ----------
__global__ __launch_bounds__(256, 7) void fusedE_kernel(const int* __restrict__ row,
                                                        const int* __restrict__ col,
                                                        const float* __restrict__ ewa,
                                                        const float* __restrict__ dinv,
                                                        const int* __restrict__ row_ptr,
                                                        const unsigned short* __restrict__ rank,
                                                        unsigned* __restrict__ edata, int E,
                                                        const float* __restrict__ hbuf,
                                                        const unsigned short* __restrict__ Wt1,
                                                        unsigned short* __restrict__ tbuf, int n,
                                                        int nGemm, int K) {
    int b = blockIdx.x;
    int g = b / K, r = b - g * K;
    if (r == 0 && g < nGemm) {
        gemm_body<true>(hbuf, Wt1, nullptr, tbuf, n, g);
    } else {
        int sb = b - min(g + (r > 0 ? 1 : 0), nGemm);
        scatter_body(row, col, ewa, dinv, row_ptr, rank, edata, E, sb);
    }
}

// ---------- standalone GEMM (layers 2,3 messages): fp32 A -> bf16 C ----------
__global__ __launch_bounds__(256, 7) void gemm_mfma_kernel(const float* __restrict__ A,
                                                           const unsigned short* __restrict__ Wt,
                                                           unsigned short* __restrict__ C, int n) {
    gemm_body<true>(A, Wt, nullptr, C, n, blockIdx.x);
}

// ---------- scan phase 1: per-1024-chunk sums of PADDED counts (x8) ----------
__global__ __launch_bounds__(256) void scan1_kernel(const unsigned long long* __restrict__ packed,
                                                    int* __restrict__ bsum, int n) {
    __shared__ int s[256];
    int b = blockIdx.x, t = threadIdx.x;
    int base = b * 1024 + t * 4;
    int acc = 0;
#pragma unroll
    for (int i = 0; i < 4; ++i)
        if (base + i < n) acc += ((int)(packed[base + i] >> 40) + 7) & ~7;
    s[t] = acc;
    __syncthreads();
    for (int off = 128; off > 0; off >>= 1) {
        if (t < off) s[t] += s[t + off];
        __syncthreads();
    }
    if (t == 0) bsum[b] = s[0];
}

// ---------- scan phase 3 (phase 2 folded in): row_ptr + dinv + edata pad zeroing ----------
__global__ __launch_bounds__(256) void scan3_kernel(const unsigned long long* __restrict__ packed,
                                                    const int* __restrict__ bsum,
                                                    int* __restrict__ row_ptr,
                                                    float* __restrict__ dinv,
                                                    unsigned* __restrict__ edata,
                                                    int n, int nblk) {
    __shared__ int s[256];
    int b = blockIdx.x, t = threadIdx.x;

    // phase A: every block redundantly computes inclusive prefix of bsum (nblk<=256)
    int bv = (t < nblk) ? bsum[t] : 0;
    s[t] = bv;
    __syncthreads();
    for (int off = 1; off < 256; off <<= 1) {
        int u = (t >= off) ? s[t - off] : 0;
        __syncthreads();
        s[t] += u;
        __syncthreads();
    }
    int boffb = (b == 0) ? 0 : s[b - 1];
    int total = s[nblk - 1];
    __syncthreads();

    // phase B: local scan of this block's 1024 padded counts
    int base = b * 1024 + t * 4;
    int c[4], v[4];
#pragma unroll
    for (int i = 0; i < 4; ++i) {
        unsigned long long p = (base + i < n) ? packed[base + i] : 0ull;
        c[i] = (int)(p >> 40);
        v[i] = (c[i] + 7) & ~7;               // padded count
        if (base + i < n) {
            float deg = 1.0f + (float)(p & 0xFFFFFFFFFFull) * (1.0f / 16777216.0f);
            dinv[base + i] = rsqrtf(deg);
        }
    }
    s[t] = v[0] + v[1] + v[2] + v[3];
    __syncthreads();
    for (int off = 1; off < 256; off <<= 1) {
        int u = (t >= off) ? s[t - off] : 0;
        __syncthreads();
        s[t] += u;
        __syncthreads();
    }
    int run = boffb + ((t == 0) ? 0 : s[t - 1]);
#pragma unroll
    for (int i = 0; i < 4; ++i) {
        if (base + i < n) {
            row_ptr[base + i] = run;
            for (int z = c[i]; z < v[i]; ++z) edata[run + z] = 0;   // zero pad slots
            run += v[i];
        }
    }
    if (b == nblk - 1 && t == 255) row_ptr[n] = total;
}

// ---------- aggregation: one wave per dest node, edge-pair batched gather ----------
// Gathers bf16 messages (tb2); accumulates fp32; writes fp32 h (or final sigmoid).
template<bool FINAL>
__global__ __launch_bounds__(256) void aggregate_kernel(const uint2* __restrict__ tb2,
                                                        const int* __restrict__ row_ptr,
                                                        const unsigned* __restrict__ edata,
                                                        const float* __restrict__ dinv,
                                                        const float* __restrict__ bias,
                                                        const float* __restrict__ W2,
                                                        const float* __restrict__ b2,
                                                        void* __restrict__ out, int n) {
    int wid  = (int)((blockIdx.x * (size_t)blockDim.x + threadIdx.x) >> 6);
    int lane = threadIdx.x & 63;
    if (wid >= n) return;
    int half = lane >> 5;     // which edge of each pair
    int fl   = lane & 31;     // feature group (4 feats)

    float a0 = 0.f, a1 = 0.f, a2 = 0.f, a3 = 0.f;

    int start = row_ptr[wid], end = row_ptr[wid + 1];
    for (int base = start; base < end; base += 64) {
        unsigned ed = edata[base + lane];     // over-read into next buckets is harmless
        int m = end - base; if (m > 64) m = 64;
        int j = 0;
        for (; j + 16 <= m; j += 16) {        // 8 pairs = 16 edges
            unsigned p[8]; uint2 u[8];
#pragma unroll
            for (int k = 0; k < 8; ++k) p[k] = __shfl(ed, j + 2 * k + half);
#pragma unroll
            for (int k = 0; k < 8; ++k) u[k] = tb2[(size_t)(p[k] >> 15) * 32 + fl];
#pragma unroll
            for (int k = 0; k < 8; ++k) {
                float w = __uint_as_float((p[k] & 0x7fffu) << 16);
                a0 += w * bf_lo(u[k].x); a1 += w * bf_hi(u[k].x);
                a2 += w * bf_lo(u[k].y); a3 += w * bf_hi(u[k].y);
            }
        }
        for (; j < m; j += 8) {               // 4 pairs = 8 edges (m is mult of 8)
            unsigned p[4]; uint2 u[4];
#pragma unroll
            for (int k = 0; k < 4; ++k) p[k] = __shfl(ed, j + 2 * k + half);
#pragma unroll
            for (int k = 0; k < 4; ++k) u[k] = tb2[(size_t)(p[k] >> 15) * 32 + fl];
#pragma unroll
            for (int k = 0; k < 4; ++k) {
                float w = __uint_as_float((p[k] & 0x7fffu) << 16);
                a0 += w * bf_lo(u[k].x); a1 += w * bf_hi(u[k].x);
                a2 += w * bf_lo(u[k].y); a3 += w * bf_hi(u[k].y);
            }
        }
    }
    // combine the two halves (lanes l and l^32 end up with identical sums)
    a0 += __shfl_xor(a0, 32); a1 += __shfl_xor(a1, 32);
    a2 += __shfl_xor(a2, 32); a3 += __shfl_xor(a3, 32);

    // self-loop + bias (mirrored across halves)
    float di = dinv[wid];
    float sn = di * di;
    uint2 ts = tb2[(size_t)wid * 32 + fl];
    a0 += sn * bf_lo(ts.x); a1 += sn * bf_hi(ts.x);
    a2 += sn * bf_lo(ts.y); a3 += sn * bf_hi(ts.y);
    float4 bb = ((const float4*)bias)[fl];
    a0 += bb.x; a1 += bb.y; a2 += bb.z; a3 += bb.w;

    if (FINAL) {
        float4 wv = ((const float4*)W2)[fl];
        float d = a0 * wv.x + a1 * wv.y + a2 * wv.z + a3 * wv.w;
        if (half) d = 0.f;                    // halves mirror: count once
#pragma unroll
        for (int off = 32; off > 0; off >>= 1) d += __shfl_xor(d, off);
        if (lane == 0) ((float*)out)[wid] = 1.0f / (1.0f + expf(-(d + b2[0])));
    } else if (half == 0) {
        float4 o; o.x = a0; o.y = a1; o.z = a2; o.w = a3;
        ((float4*)out)[(size_t)wid * 32 + fl] = o;   // fp32 h state
    }
}

static inline char* align16(char* p) { return (char*)(((uintptr_t)p + 15) & ~(uintptr_t)15); }

extern "C" void kernel_launch(void* const* d_in, const int* in_sizes, int n_in,
                              void* d_out, int out_size, void* d_ws, size_t ws_size,
                              hipStream_t stream) {
    const float* x  = (const float*)d_in[0];
    const int*   ei = (const int*)d_in[1];   // [2, E] int32
    const float* ea = (const float*)d_in[2]; // [E]
    const float* W1 = (const float*)d_in[3];
    const float* b1 = (const float*)d_in[4];
    const float* Wg = (const float*)d_in[5]; // [3,128,128]
    const float* bg = (const float*)d_in[6]; // [3,128]
    const float* W2 = (const float*)d_in[7]; // [128]
    const float* b2 = (const float*)d_in[8]; // [1]

    const int N = in_sizes[0] / 128;
    const int E = in_sizes[2];
    const int Npad = (N + 63) & ~63;
    const int* row = ei;
    const int* col = ei + E;

    // workspace layout
    char* p = (char*)d_ws;
    float*          hbuf = (float*)p;          p += (size_t)Npad * 128 * 4;  // fp32 state
    unsigned short* tbuf = (unsigned short*)p; p += (size_t)Npad * 128 * 2;  // bf16 messages
    unsigned short* wbuf = (unsigned short*)p; p += 4 * 16384 * 2;           // bf16 W^T x4
    p = align16(p);
    unsigned long long* packed = (unsigned long long*)p; p += (size_t)N * 8;
    float* dinv   = (float*)p; p += (size_t)N * 4;
    int* row_ptr  = (int*)p;   p += (size_t)(N + 1) * 4; p = align16(p);
    int* bsum     = (int*)p;   p += 256 * 4;
    unsigned short* rank = (unsigned short*)p; p += (size_t)E * 2; p = align16(p);
    unsigned* edata = (unsigned*)p;                    // E + 7N + 64 padded records

    dim3 b256(256);
    int nblk  = (N + 1023) / 1024;          // 98 (<=256)
    int nGemm = Npad / 64;                  // 1563
    int nHist = (E + 255) / 256;            // 6250
    int nScat = (E + 1023) / 1024;          // 1563
    int nPrep = (max(N, 65536) + 255) / 256;

    int gridA = nHist + nGemm;
    int KA    = (gridA + nGemm - 1) / nGemm;   // 5
    int gridE = nScat + nGemm;
    int KE    = (gridE + nGemm - 1) / nGemm;   // 2

    prep_kernel<<<nPrep, b256, 0, stream>>>(W1, Wg, wbuf, packed, N);
    fusedA_kernel<<<gridA, b256, 0, stream>>>(col, ea, packed, rank, E,
                                              x, wbuf, b1, hbuf, N, nGemm, KA);
    scan1_kernel <<<nblk, b256, 0, stream>>>(packed, bsum, N);
    scan3_kernel <<<nblk, b256, 0, stream>>>(packed, bsum, row_ptr, dinv, edata, N, nblk);
    fusedE_kernel<<<gridE, b256, 0, stream>>>(row, col, ea, dinv, row_ptr, rank, edata, E,
                                              hbuf, wbuf + 16384, tbuf, N, nGemm, KE);

    int wave_blocks = (int)(((size_t)N * 64 + 255) / 256);

    // agg0 -> hbuf(fp32); gemm(l=1) -> tbuf; agg1 -> hbuf; gemm(l=2) -> tbuf; agg2 -> out
    aggregate_kernel<false><<<wave_blocks, b256, 0, stream>>>(
        (const uint2*)tbuf, row_ptr, edata, dinv, bg, nullptr, nullptr, hbuf, N);
    gemm_mfma_kernel<<<nGemm, b256, 0, stream>>>(hbuf, wbuf + 2 * 16384, tbuf, N);
    aggregate_kernel<false><<<wave_blocks, b256, 0, stream>>>(
        (const uint2*)tbuf, row_ptr, edata, dinv, bg + 128, nullptr, nullptr, hbuf, N);
    gemm_mfma_kernel<<<nGemm, b256, 0, stream>>>(hbuf, wbuf + 3 * 16384, tbuf, N);
    aggregate_kernel<true><<<wave_blocks, b256, 0, stream>>>(
        (const uint2*)tbuf, row_ptr, edata, dinv, bg + 256, W2, b2, d_out, N);
}

// Round 9
// 518.977 us; speedup vs baseline: 1.0227x; 1.0227x over previous
//
#include <hip/hip_runtime.h>
#include <cstdint>
#include <cstddef>

// SimpleGCN: h = x@W1+b1; 3x GCNConv(sym-norm adj w/ self loops); sigmoid(h@W2+b2)
// N=100000, d=128, E=1.6M.
// R9: (a) revert R8's 16-row gemm tile (cost +23us; occupancy was NOT the histo
//     limiter -- atomic floor ~22G/s is memory-side, fusedA ~= serial either way),
//     (b) NEW: aggregate+GEMM fused per block via 64x128 LDS h-tile: kills the
//     51MB hbuf write + 51MB read per middle layer (~37us) + 2 launches.
// Numerics (replay-stable, per R6 failure / R7 fix): agg sums fp32; h quantized
// to bf16 only as MFMA input (in-register); messages/weights bf16.

typedef __attribute__((ext_vector_type(8))) short bf16x8;
typedef __attribute__((ext_vector_type(4))) float f32x4;

// ---------- bf16 helpers (packed dword: low 16 bits = element 0) ----------
__device__ __forceinline__ unsigned f2bf(float f) {      // RNE float->bf16 bits
    unsigned u = __float_as_uint(f);
    u += 0x7fffu + ((u >> 16) & 1u);
    return u >> 16;
}
__device__ __forceinline__ float bf_lo(unsigned p) { return __uint_as_float(p << 16); }
__device__ __forceinline__ float bf_hi(unsigned p) { return __uint_as_float(p & 0xffff0000u); }

// ---------- prep: bf16 W^T for all 4 layers + zero the packed histogram ----------
__global__ void prep_kernel(const float* __restrict__ W1, const float* __restrict__ Wg,
                            unsigned short* __restrict__ Wt,
                            unsigned long long* __restrict__ packed, int n) {
    int idx = blockIdx.x * blockDim.x + threadIdx.x;
    if (idx < 65536) {
        int l = idx >> 14, nn = (idx >> 7) & 127, k = idx & 127;
        const float* W = (l == 0) ? W1 : (Wg + (size_t)(l - 1) * 16384);
        Wt[idx] = (unsigned short)f2bf(W[k * 128 + nn]);
    }
    if (idx < n) packed[idx] = 0ull;
}

// ---------- GEMM body (R7 32x128 wave tile): C = A(fp32)@W (+bias) ----------
// No LDS/barriers; Wt (bf16 W^T) is L1/L2-resident. C bf16 or fp32.
template<bool C_BF16>
__device__ __forceinline__ void gemm_body32(const float* __restrict__ A,
                                            const unsigned short* __restrict__ Wt,
                                            const float* __restrict__ bias,
                                            void* __restrict__ C, int n, int blk) {
    int tid = threadIdx.x;
    int wave = tid >> 6, lane = tid & 63;
    int lm = lane & 15, g = lane >> 4;
    int m_base = blk * 128 + wave * 32;

    f32x4 acc[2][8];
#pragma unroll
    for (int rt = 0; rt < 2; ++rt)
#pragma unroll
        for (int ct = 0; ct < 8; ++ct) acc[rt][ct] = (f32x4){0.f, 0.f, 0.f, 0.f};

    size_t rowA[2];
    rowA[0] = (size_t)min(m_base + lm, n - 1);
    rowA[1] = (size_t)min(m_base + 16 + lm, n - 1);

#pragma unroll
    for (int kc = 0; kc < 4; ++kc) {
        int k0 = kc * 32 + g * 8;
        bf16x8 a[2];
#pragma unroll
        for (int rt = 0; rt < 2; ++rt) {
            const float* p = A + rowA[rt] * 128 + k0;
            float f[8];
            *(float4*)&f[0] = *(const float4*)p;
            *(float4*)&f[4] = *(const float4*)(p + 4);
            short sv[8];
#pragma unroll
            for (int j = 0; j < 8; ++j) sv[j] = (short)f2bf(f[j]);
            a[rt] = *(bf16x8*)sv;
        }
        bf16x8 b[8];
#pragma unroll
        for (int ct = 0; ct < 8; ++ct)
            b[ct] = *(const bf16x8*)(Wt + (ct * 16 + lm) * 128 + k0);
#pragma unroll
        for (int ct = 0; ct < 8; ++ct) {
            acc[0][ct] = __builtin_amdgcn_mfma_f32_16x16x32_bf16(a[0], b[ct], acc[0][ct], 0, 0, 0);
            acc[1][ct] = __builtin_amdgcn_mfma_f32_16x16x32_bf16(a[1], b[ct], acc[1][ct], 0, 0, 0);
        }
    }

#pragma unroll
    for (int rt = 0; rt < 2; ++rt) {
#pragma unroll
        for (int r = 0; r < 4; ++r) {
            int grow = m_base + rt * 16 + g * 4 + r;
            if (grow < n) {
#pragma unroll
                for (int ct = 0; ct < 8; ++ct) {
                    float v = acc[rt][ct][r];
                    if (bias) v += bias[ct * 16 + lm];
                    if (C_BF16)
                        ((unsigned short*)C)[(size_t)grow * 128 + ct * 16 + lm] = (unsigned short)f2bf(v);
                    else
                        ((float*)C)[(size_t)grow * 128 + ct * 16 + lm] = v;
                }
            }
        }
    }
}

// ---------- scatter body (NO atomics): pos = row_ptr[c] + rank[e], 4 edges/thread ----------
// record = (src << 15) | (bf16(norm) & 0x7fff); norm > 0 so sign bit unused.
__device__ __forceinline__ void scatter_body(const int* __restrict__ row, const int* __restrict__ col,
                                             const float* __restrict__ ew, const float* __restrict__ dinv,
                                             const int* __restrict__ row_ptr,
                                             const unsigned short* __restrict__ rank,
                                             unsigned* __restrict__ edata, int E, int blk) {
    int e0 = (blk * 256 + threadIdx.x) * 4;
    if (e0 + 3 < E) {
        int4   r4 = *(const int4*)(row + e0);
        int4   c4 = *(const int4*)(col + e0);
        float4 w4 = *(const float4*)(ew + e0);
        ushort4 k4 = *(const ushort4*)(rank + e0);
        int   r[4] = {r4.x, r4.y, r4.z, r4.w};
        int   c[4] = {c4.x, c4.y, c4.z, c4.w};
        float w[4] = {w4.x, w4.y, w4.z, w4.w};
        unsigned short kk[4] = {k4.x, k4.y, k4.z, k4.w};
#pragma unroll
        for (int i = 0; i < 4; ++i) {
            float nrm = dinv[r[i]] * w[i] * dinv[c[i]];
            int pos = row_ptr[c[i]] + (int)kk[i];
            edata[pos] = ((unsigned)r[i] << 15) | (f2bf(nrm) & 0x7fffu);
        }
    } else {
        for (int e = e0; e < E; ++e) {
            int r = row[e], c = col[e];
            float nrm = dinv[r] * ew[e] * dinv[c];
            int pos = row_ptr[c] + (int)rank[e];
            edata[pos] = ((unsigned)r << 15) | (f2bf(nrm) & 0x7fffu);
        }
    }
}

// ---------- fused A: histo (1 u64 atomic/edge + rank) || gemm1 (x@W1+b1 -> fp32 h) ----------
__global__ __launch_bounds__(256) void fusedA_kernel(const int* __restrict__ col,
                                                     const float* __restrict__ ewa,
                                                     unsigned long long* __restrict__ packed,
                                                     unsigned short* __restrict__ rank, int E,
                                                     const float* __restrict__ x,
                                                     const unsigned short* __restrict__ Wt0,
                                                     const float* __restrict__ b1,
                                                     float* __restrict__ hbuf, int n,
                                                     int nGemm, int K) {
    int b = blockIdx.x;
    int g = b / K, r = b - g * K;
    if (r == 0 && g < nGemm) {
        gemm_body32<false>(x, Wt0, b1, hbuf, n, g);
    } else {
        int hb = b - min(g + (r > 0 ? 1 : 0), nGemm);
        int e = hb * 256 + threadIdx.x;
        if (e < E) {
            int c = col[e];
            unsigned long long v = (1ull << 40) |
                (unsigned long long)(unsigned)(ewa[e] * 16777216.0f);
            unsigned long long old = atomicAdd(&packed[c], v);
            rank[e] = (unsigned short)(old >> 40);
        }
    }
}

// ---------- fused E: scatter || gemm2 (hbuf@Wg0 -> tbuf bf16) ----------
__global__ __launch_bounds__(256) void fusedE_kernel(const int* __restrict__ row,
                                                     const int* __restrict__ col,
                                                     const float* __restrict__ ewa,
                                                     const float* __restrict__ dinv,
                                                     const int* __restrict__ row_ptr,
                                                     const unsigned short* __restrict__ rank,
                                                     unsigned* __restrict__ edata, int E,
                                                     const float* __restrict__ hbuf,
                                                     const unsigned short* __restrict__ Wt1,
                                                     unsigned short* __restrict__ tbuf, int n,
                                                     int nGemm, int K) {
    int b = blockIdx.x;
    int g = b / K, r = b - g * K;
    if (r == 0 && g < nGemm) {
        gemm_body32<true>(hbuf, Wt1, nullptr, tbuf, n, g);
    } else {
        int sb = b - min(g + (r > 0 ? 1 : 0), nGemm);
        scatter_body(row, col, ewa, dinv, row_ptr, rank, edata, E, sb);
    }
}

// ---------- scan phase 1: per-1024-chunk sums of PADDED counts (x8) ----------
__global__ __launch_bounds__(256) void scan1_kernel(const unsigned long long* __restrict__ packed,
                                                    int* __restrict__ bsum, int n) {
    __shared__ int s[256];
    int b = blockIdx.x, t = threadIdx.x;
    int base = b * 1024 + t * 4;
    int acc = 0;
#pragma unroll
    for (int i = 0; i < 4; ++i)
        if (base + i < n) acc += ((int)(packed[base + i] >> 40) + 7) & ~7;
    s[t] = acc;
    __syncthreads();
    for (int off = 128; off > 0; off >>= 1) {
        if (t < off) s[t] += s[t + off];
        __syncthreads();
    }
    if (t == 0) bsum[b] = s[0];
}

// ---------- scan phase 3 (phase 2 folded in): row_ptr + dinv + edata pad zeroing ----------
__global__ __launch_bounds__(256) void scan3_kernel(const unsigned long long* __restrict__ packed,
                                                    const int* __restrict__ bsum,
                                                    int* __restrict__ row_ptr,
                                                    float* __restrict__ dinv,
                                                    unsigned* __restrict__ edata,
                                                    int n, int nblk) {
    __shared__ int s[256];
    int b = blockIdx.x, t = threadIdx.x;

    int bv = (t < nblk) ? bsum[t] : 0;
    s[t] = bv;
    __syncthreads();
    for (int off = 1; off < 256; off <<= 1) {
        int u = (t >= off) ? s[t - off] : 0;
        __syncthreads();
        s[t] += u;
        __syncthreads();
    }
    int boffb = (b == 0) ? 0 : s[b - 1];
    int total = s[nblk - 1];
    __syncthreads();

    int base = b * 1024 + t * 4;
    int c[4], v[4];
#pragma unroll
    for (int i = 0; i < 4; ++i) {
        unsigned long long p = (base + i < n) ? packed[base + i] : 0ull;
        c[i] = (int)(p >> 40);
        v[i] = (c[i] + 7) & ~7;               // padded count
        if (base + i < n) {
            float deg = 1.0f + (float)(p & 0xFFFFFFFFFFull) * (1.0f / 16777216.0f);
            dinv[base + i] = rsqrtf(deg);
        }
    }
    s[t] = v[0] + v[1] + v[2] + v[3];
    __syncthreads();
    for (int off = 1; off < 256; off <<= 1) {
        int u = (t >= off) ? s[t - off] : 0;
        __syncthreads();
        s[t] += u;
        __syncthreads();
    }
    int run = boffb + ((t == 0) ? 0 : s[t - 1]);
#pragma unroll
    for (int i = 0; i < 4; ++i) {
        if (base + i < n) {
            row_ptr[base + i] = run;
            for (int z = c[i]; z < v[i]; ++z) edata[run + z] = 0;   // zero pad slots
            run += v[i];
        }
    }
    if (b == nblk - 1 && t == 255) row_ptr[n] = total;
}

// ---------- per-node aggregation body (edge-pair batched gather) ----------
// Returns fp32 sums (incl self-loop + bias), MIRRORED across the two 32-lane
// halves. half = lane>>5, fl = lane&31 (feature group of 4).
__device__ __forceinline__ void agg_node(const uint2* __restrict__ tb2,
                                         const int* __restrict__ row_ptr,
                                         const unsigned* __restrict__ edata,
                                         const float* __restrict__ dinv,
                                         const float* __restrict__ bias,
                                         int wid, int lane, int half, int fl,
                                         float& a0, float& a1, float& a2, float& a3) {
    a0 = a1 = a2 = a3 = 0.f;
    int start = row_ptr[wid], end = row_ptr[wid + 1];
    for (int base = start; base < end; base += 64) {
        unsigned ed = edata[base + lane];     // over-read into next buckets is harmless
        int m = end - base; if (m > 64) m = 64;
        int j = 0;
        for (; j + 16 <= m; j += 16) {        // 8 pairs = 16 edges
            unsigned p[8]; uint2 u[8];
#pragma unroll
            for (int k = 0; k < 8; ++k) p[k] = __shfl(ed, j + 2 * k + half);
#pragma unroll
            for (int k = 0; k < 8; ++k) u[k] = tb2[(size_t)(p[k] >> 15) * 32 + fl];
#pragma unroll
            for (int k = 0; k < 8; ++k) {
                float w = __uint_as_float((p[k] & 0x7fffu) << 16);
                a0 += w * bf_lo(u[k].x); a1 += w * bf_hi(u[k].x);
                a2 += w * bf_lo(u[k].y); a3 += w * bf_hi(u[k].y);
            }
        }
        for (; j < m; j += 8) {               // 4 pairs = 8 edges (m is mult of 8)
            unsigned p[4]; uint2 u[4];
#pragma unroll
            for (int k = 0; k < 4; ++k) p[k] = __shfl(ed, j + 2 * k + half);
#pragma unroll
            for (int k = 0; k < 4; ++k) u[k] = tb2[(size_t)(p[k] >> 15) * 32 + fl];
#pragma unroll
            for (int k = 0; k < 4; ++k) {
                float w = __uint_as_float((p[k] & 0x7fffu) << 16);
                a0 += w * bf_lo(u[k].x); a1 += w * bf_hi(u[k].x);
                a2 += w * bf_lo(u[k].y); a3 += w * bf_hi(u[k].y);
            }
        }
    }
    a0 += __shfl_xor(a0, 32); a1 += __shfl_xor(a1, 32);
    a2 += __shfl_xor(a2, 32); a3 += __shfl_xor(a3, 32);

    float di = dinv[wid];
    float sn = di * di;                       // self-loop norm = 1/deg
    uint2 ts = tb2[(size_t)wid * 32 + fl];
    a0 += sn * bf_lo(ts.x); a1 += sn * bf_hi(ts.x);
    a2 += sn * bf_lo(ts.y); a3 += sn * bf_hi(ts.y);
    float4 bb = ((const float4*)bias)[fl];
    a0 += bb.x; a1 += bb.y; a2 += bb.z; a3 += bb.w;
}

// ---------- fused aggregate + GEMM (middle layers) ----------
// Block = 64 dest nodes. Phase 1: 4 waves x 16 nodes aggregate -> fp32 h rows
// in LDS (stride 132 to break bank alignment). Phase 2: each wave computes a
// 16x128 MFMA tile (A from LDS, bf16-converted in-register) -> next messages.
#define HSTRIDE 132
__global__ __launch_bounds__(256) void aggGemm_kernel(const uint2* __restrict__ tb2,
                                                      const int* __restrict__ row_ptr,
                                                      const unsigned* __restrict__ edata,
                                                      const float* __restrict__ dinv,
                                                      const float* __restrict__ bias,
                                                      const unsigned short* __restrict__ Wt,
                                                      unsigned short* __restrict__ outMsg,
                                                      int n) {
    __shared__ float hls[64 * HSTRIDE];
    int b = blockIdx.x;
    int tid = threadIdx.x;
    int wave = tid >> 6, lane = tid & 63;
    int half = lane >> 5, fl = lane & 31;

    // phase 1: aggregate 16 nodes per wave into LDS
    for (int i = 0; i < 16; ++i) {
        int lrow = wave * 16 + i;
        int wid = b * 64 + lrow;
        if (wid < n) {
            float a0, a1, a2, a3;
            agg_node(tb2, row_ptr, edata, dinv, bias, wid, lane, half, fl, a0, a1, a2, a3);
            if (half == 0) {
                float4 o; o.x = a0; o.y = a1; o.z = a2; o.w = a3;
                *(float4*)&hls[lrow * HSTRIDE + fl * 4] = o;
            }
        } else if (half == 0) {
            float4 z; z.x = z.y = z.z = z.w = 0.f;
            *(float4*)&hls[lrow * HSTRIDE + fl * 4] = z;
        }
    }
    __syncthreads();

    // phase 2: 16x128 MFMA tile per wave, A rows from LDS
    int lm = lane & 15, g = lane >> 4;
    int lbase = wave * 16 + lm;
    f32x4 acc[8];
#pragma unroll
    for (int ct = 0; ct < 8; ++ct) acc[ct] = (f32x4){0.f, 0.f, 0.f, 0.f};

#pragma unroll
    for (int kc = 0; kc < 4; ++kc) {
        int k0 = kc * 32 + g * 8;
        bf16x8 a;
        {
            float f[8];
            *(float4*)&f[0] = *(const float4*)&hls[lbase * HSTRIDE + k0];
            *(float4*)&f[4] = *(const float4*)&hls[lbase * HSTRIDE + k0 + 4];
            short sv[8];
#pragma unroll
            for (int j = 0; j < 8; ++j) sv[j] = (short)f2bf(f[j]);
            a = *(bf16x8*)sv;
        }
#pragma unroll
        for (int ct = 0; ct < 8; ++ct) {
            bf16x8 bw = *(const bf16x8*)(Wt + (ct * 16 + lm) * 128 + k0);
            acc[ct] = __builtin_amdgcn_mfma_f32_16x16x32_bf16(a, bw, acc[ct], 0, 0, 0);
        }
    }

#pragma unroll
    for (int r = 0; r < 4; ++r) {
        int grow = b * 64 + wave * 16 + g * 4 + r;
        if (grow < n) {
#pragma unroll
            for (int ct = 0; ct < 8; ++ct)
                outMsg[(size_t)grow * 128 + ct * 16 + lm] = (unsigned short)f2bf(acc[ct][r]);
        }
    }
}

// ---------- final aggregate + gemv + sigmoid ----------
__global__ __launch_bounds__(256) void aggFinal_kernel(const uint2* __restrict__ tb2,
                                                       const int* __restrict__ row_ptr,
                                                       const unsigned* __restrict__ edata,
                                                       const float* __restrict__ dinv,
                                                       const float* __restrict__ bias,
                                                       const float* __restrict__ W2,
                                                       const float* __restrict__ b2,
                                                       float* __restrict__ out, int n) {
    int wid  = (int)((blockIdx.x * (size_t)blockDim.x + threadIdx.x) >> 6);
    int lane = threadIdx.x & 63;
    if (wid >= n) return;
    int half = lane >> 5, fl = lane & 31;
    float a0, a1, a2, a3;
    agg_node(tb2, row_ptr, edata, dinv, bias, wid, lane, half, fl, a0, a1, a2, a3);
    float4 wv = ((const float4*)W2)[fl];
    float d = a0 * wv.x + a1 * wv.y + a2 * wv.z + a3 * wv.w;
    if (half) d = 0.f;                        // halves mirror: count once
#pragma unroll
    for (int off = 32; off > 0; off >>= 1) d += __shfl_xor(d, off);
    if (lane == 0) out[wid] = 1.0f / (1.0f + expf(-(d + b2[0])));
}

static inline char* align16(char* p) { return (char*)(((uintptr_t)p + 15) & ~(uintptr_t)15); }

extern "C" void kernel_launch(void* const* d_in, const int* in_sizes, int n_in,
                              void* d_out, int out_size, void* d_ws, size_t ws_size,
                              hipStream_t stream) {
    const float* x  = (const float*)d_in[0];
    const int*   ei = (const int*)d_in[1];   // [2, E] int32
    const float* ea = (const float*)d_in[2]; // [E]
    const float* W1 = (const float*)d_in[3];
    const float* b1 = (const float*)d_in[4];
    const float* Wg = (const float*)d_in[5]; // [3,128,128]
    const float* bg = (const float*)d_in[6]; // [3,128]
    const float* W2 = (const float*)d_in[7]; // [128]
    const float* b2 = (const float*)d_in[8]; // [1]

    const int N = in_sizes[0] / 128;
    const int E = in_sizes[2];
    const int Npad = (N + 127) & ~127;
    const int* row = ei;
    const int* col = ei + E;

    // workspace layout
    char* p = (char*)d_ws;
    float*          hbuf  = (float*)p;          p += (size_t)Npad * 128 * 4;  // fp32 h1
    unsigned short* tbufA = (unsigned short*)p; p += (size_t)Npad * 128 * 2;  // bf16 msgs
    unsigned short* tbufB = (unsigned short*)p; p += (size_t)Npad * 128 * 2;  // bf16 msgs
    unsigned short* wbuf  = (unsigned short*)p; p += 4 * 16384 * 2;           // bf16 W^T x4
    p = align16(p);
    unsigned long long* packed = (unsigned long long*)p; p += (size_t)N * 8;
    float* dinv   = (float*)p; p += (size_t)N * 4;
    int* row_ptr  = (int*)p;   p += (size_t)(N + 1) * 4; p = align16(p);
    int* bsum     = (int*)p;   p += 256 * 4;
    unsigned short* rank = (unsigned short*)p; p += (size_t)E * 2; p = align16(p);
    unsigned* edata = (unsigned*)p;                    // E + 7N + 64 padded records

    dim3 b256(256);
    int nblk  = (N + 1023) / 1024;          // 98 (<=256)
    int nGemm = Npad / 128;                 // 782
    int nHist = (E + 255) / 256;            // 6250
    int nScat = (E + 1023) / 1024;          // 1563
    int nAgg  = (N + 63) / 64;              // 1563
    int nPrep = (max(N, 65536) + 255) / 256;

    int gridA = nHist + nGemm;
    int KA    = (gridA + nGemm - 1) / nGemm;   // 9
    int gridE = nScat + nGemm;
    int KE    = (gridE + nGemm - 1) / nGemm;   // 3

    prep_kernel<<<nPrep, b256, 0, stream>>>(W1, Wg, wbuf, packed, N);
    fusedA_kernel<<<gridA, b256, 0, stream>>>(col, ea, packed, rank, E,
                                              x, wbuf, b1, hbuf, N, nGemm, KA);
    scan1_kernel <<<nblk, b256, 0, stream>>>(packed, bsum, N);
    scan3_kernel <<<nblk, b256, 0, stream>>>(packed, bsum, row_ptr, dinv, edata, N, nblk);
    fusedE_kernel<<<gridE, b256, 0, stream>>>(row, col, ea, dinv, row_ptr, rank, edata, E,
                                              hbuf, wbuf + 16384, tbufA, N, nGemm, KE);

    // layer0: agg(tbufA)+bg0 -> h1 -> @Wg1 -> tbufB
    aggGemm_kernel<<<nAgg, b256, 0, stream>>>((const uint2*)tbufA, row_ptr, edata, dinv,
                                              bg, wbuf + 2 * 16384, tbufB, N);
    // layer1: agg(tbufB)+bg1 -> h2 -> @Wg2 -> tbufA
    aggGemm_kernel<<<nAgg, b256, 0, stream>>>((const uint2*)tbufB, row_ptr, edata, dinv,
                                              bg + 128, wbuf + 3 * 16384, tbufA, N);
    // layer2: agg(tbufA)+bg2 -> sigmoid(h3@W2+b2) -> out
    int wave_blocks = (int)(((size_t)N * 64 + 255) / 256);
    aggFinal_kernel<<<wave_blocks, b256, 0, stream>>>((const uint2*)tbufA, row_ptr, edata, dinv,
                                                      bg + 256, W2, b2, (float*)d_out, N);
}

// Round 10
// 490.801 us; speedup vs baseline: 1.0814x; 1.0574x over previous
//
#include <hip/hip_runtime.h>
#include <cstdint>
#include <cstddef>

// SimpleGCN: h = x@W1+b1; 3x GCNConv(sym-norm adj w/ self loops); sigmoid(h@W2+b2)
// N=100000, d=128, E=1.6M.
// R10 = R7 skeleton (beat R8/R9 restructurings) + bf16 h1:
//   h1 = x@W1+b1 is a pure GEMM output (deterministic across replays -- the
//   replay-stability invariant only forbids bf16 for ATOMIC-ORDER-dependent
//   aggregate sums). Storing h1 bf16 cuts fusedA write 103->78MB and fusedE
//   A-read 51->26MB. Middle h stays fp32 (R6 failure mode lives there).
//   Histo vectorized 4 edges/thread (atomic count unchanged = 22G/s floor).
// Measured floors (don't re-attack): histo 74us (atomic rate), aggregate ~70us
// x3 (random-gather fabric), atomic+MFMA don't co-schedule (R8: occupancy was
// not the limiter; R9: LDS fusion neutral).

typedef __attribute__((ext_vector_type(8))) short bf16x8;
typedef __attribute__((ext_vector_type(4))) float f32x4;

// ---------- bf16 helpers (packed dword: low 16 bits = element 0) ----------
__device__ __forceinline__ unsigned f2bf(float f) {      // RNE float->bf16 bits
    unsigned u = __float_as_uint(f);
    u += 0x7fffu + ((u >> 16) & 1u);
    return u >> 16;
}
__device__ __forceinline__ float bf_lo(unsigned p) { return __uint_as_float(p << 16); }
__device__ __forceinline__ float bf_hi(unsigned p) { return __uint_as_float(p & 0xffff0000u); }

// ---------- prep: bf16 W^T for all 4 layers + zero the packed histogram ----------
__global__ void prep_kernel(const float* __restrict__ W1, const float* __restrict__ Wg,
                            unsigned short* __restrict__ Wt,
                            unsigned long long* __restrict__ packed, int n) {
    int idx = blockIdx.x * blockDim.x + threadIdx.x;
    if (idx < 65536) {
        int l = idx >> 14, nn = (idx >> 7) & 127, k = idx & 127;
        const float* W = (l == 0) ? W1 : (Wg + (size_t)(l - 1) * 16384);
        Wt[idx] = (unsigned short)f2bf(W[k * 128 + nn]);
    }
    if (idx < n) packed[idx] = 0ull;
}

// ---------- GEMM body (32x128 wave tile): C(bf16) = A @ W (+bias) ----------
// No LDS/barriers; Wt (bf16 W^T) is L1/L2-resident. A fp32 (converted
// in-register) or bf16 (direct vector load).
template<bool A_FP32>
__device__ __forceinline__ void gemm_body32(const void* __restrict__ Av,
                                            const unsigned short* __restrict__ Wt,
                                            const float* __restrict__ bias,
                                            unsigned short* __restrict__ C, int n, int blk) {
    int tid = threadIdx.x;
    int wave = tid >> 6, lane = tid & 63;
    int lm = lane & 15, g = lane >> 4;
    int m_base = blk * 128 + wave * 32;

    f32x4 acc[2][8];
#pragma unroll
    for (int rt = 0; rt < 2; ++rt)
#pragma unroll
        for (int ct = 0; ct < 8; ++ct) acc[rt][ct] = (f32x4){0.f, 0.f, 0.f, 0.f};

    size_t rowA[2];
    rowA[0] = (size_t)min(m_base + lm, n - 1);
    rowA[1] = (size_t)min(m_base + 16 + lm, n - 1);

#pragma unroll
    for (int kc = 0; kc < 4; ++kc) {
        int k0 = kc * 32 + g * 8;
        bf16x8 a[2];
        if (A_FP32) {
            const float* A = (const float*)Av;
#pragma unroll
            for (int rt = 0; rt < 2; ++rt) {
                const float* p = A + rowA[rt] * 128 + k0;
                float f[8];
                *(float4*)&f[0] = *(const float4*)p;
                *(float4*)&f[4] = *(const float4*)(p + 4);
                short sv[8];
#pragma unroll
                for (int j = 0; j < 8; ++j) sv[j] = (short)f2bf(f[j]);
                a[rt] = *(bf16x8*)sv;
            }
        } else {
            const unsigned short* A = (const unsigned short*)Av;
#pragma unroll
            for (int rt = 0; rt < 2; ++rt)
                a[rt] = *(const bf16x8*)(A + rowA[rt] * 128 + k0);
        }
        bf16x8 b[8];
#pragma unroll
        for (int ct = 0; ct < 8; ++ct)
            b[ct] = *(const bf16x8*)(Wt + (ct * 16 + lm) * 128 + k0);
#pragma unroll
        for (int ct = 0; ct < 8; ++ct) {
            acc[0][ct] = __builtin_amdgcn_mfma_f32_16x16x32_bf16(a[0], b[ct], acc[0][ct], 0, 0, 0);
            acc[1][ct] = __builtin_amdgcn_mfma_f32_16x16x32_bf16(a[1], b[ct], acc[1][ct], 0, 0, 0);
        }
    }

#pragma unroll
    for (int rt = 0; rt < 2; ++rt) {
#pragma unroll
        for (int r = 0; r < 4; ++r) {
            int grow = m_base + rt * 16 + g * 4 + r;
            if (grow < n) {
#pragma unroll
                for (int ct = 0; ct < 8; ++ct) {
                    float v = acc[rt][ct][r];
                    if (bias) v += bias[ct * 16 + lm];
                    C[(size_t)grow * 128 + ct * 16 + lm] = (unsigned short)f2bf(v);
                }
            }
        }
    }
}

// ---------- scatter body (NO atomics): pos = row_ptr[c] + rank[e], 4 edges/thread ----------
// record = (src << 15) | (bf16(norm) & 0x7fff); norm > 0 so sign bit unused.
__device__ __forceinline__ void scatter_body(const int* __restrict__ row, const int* __restrict__ col,
                                             const float* __restrict__ ew, const float* __restrict__ dinv,
                                             const int* __restrict__ row_ptr,
                                             const unsigned short* __restrict__ rank,
                                             unsigned* __restrict__ edata, int E, int blk) {
    int e0 = (blk * 256 + threadIdx.x) * 4;
    if (e0 + 3 < E) {
        int4   r4 = *(const int4*)(row + e0);
        int4   c4 = *(const int4*)(col + e0);
        float4 w4 = *(const float4*)(ew + e0);
        ushort4 k4 = *(const ushort4*)(rank + e0);
        int   r[4] = {r4.x, r4.y, r4.z, r4.w};
        int   c[4] = {c4.x, c4.y, c4.z, c4.w};
        float w[4] = {w4.x, w4.y, w4.z, w4.w};
        unsigned short kk[4] = {k4.x, k4.y, k4.z, k4.w};
#pragma unroll
        for (int i = 0; i < 4; ++i) {
            float nrm = dinv[r[i]] * w[i] * dinv[c[i]];
            int pos = row_ptr[c[i]] + (int)kk[i];
            edata[pos] = ((unsigned)r[i] << 15) | (f2bf(nrm) & 0x7fffu);
        }
    } else {
        for (int e = e0; e < E; ++e) {
            int r = row[e], c = col[e];
            float nrm = dinv[r] * ew[e] * dinv[c];
            int pos = row_ptr[c] + (int)rank[e];
            edata[pos] = ((unsigned)r << 15) | (f2bf(nrm) & 0x7fffu);
        }
    }
}

// ---------- fused A: histo (4 edges/thread, 1 u64 atomic each) || gemm1 -> bf16 h1 ----------
__global__ __launch_bounds__(256) void fusedA_kernel(const int* __restrict__ col,
                                                     const float* __restrict__ ewa,
                                                     unsigned long long* __restrict__ packed,
                                                     unsigned short* __restrict__ rank, int E,
                                                     const float* __restrict__ x,
                                                     const unsigned short* __restrict__ Wt0,
                                                     const float* __restrict__ b1,
                                                     unsigned short* __restrict__ h1, int n,
                                                     int nGemm, int K) {
    int b = blockIdx.x;
    int g = b / K, r = b - g * K;
    if (r == 0 && g < nGemm) {
        gemm_body32<true>(x, Wt0, b1, h1, n, g);
    } else {
        int hb = b - min(g + (r > 0 ? 1 : 0), nGemm);
        int e0 = (hb * 256 + threadIdx.x) * 4;
        if (e0 + 3 < E) {
            int4   c4 = *(const int4*)(col + e0);
            float4 w4 = *(const float4*)(ewa + e0);
            int   c[4] = {c4.x, c4.y, c4.z, c4.w};
            float w[4] = {w4.x, w4.y, w4.z, w4.w};
            unsigned short rk[4];
#pragma unroll
            for (int i = 0; i < 4; ++i) {
                unsigned long long v = (1ull << 40) |
                    (unsigned long long)(unsigned)(w[i] * 16777216.0f);
                unsigned long long old = atomicAdd(&packed[c[i]], v);
                rk[i] = (unsigned short)(old >> 40);
            }
            *(ushort4*)(rank + e0) = make_ushort4(rk[0], rk[1], rk[2], rk[3]);
        } else {
            for (int e = e0; e < E; ++e) {
                unsigned long long v = (1ull << 40) |
                    (unsigned long long)(unsigned)(ewa[e] * 16777216.0f);
                unsigned long long old = atomicAdd(&packed[col[e]], v);
                rank[e] = (unsigned short)(old >> 40);
            }
        }
    }
}

// ---------- fused E: scatter || gemm2 (bf16 h1 @ Wg0 -> tbuf bf16) ----------
__global__ __launch_bounds__(256) void fusedE_kernel(const int* __restrict__ row,
                                                     const int* __restrict__ col,
                                                     const float* __restrict__ ewa,
                                                     const float* __restrict__ dinv,
                                                     const int* __restrict__ row_ptr,
                                                     const unsigned short* __restrict__ rank,
                                                     unsigned* __restrict__ edata, int E,
                                                     const unsigned short* __restrict__ h1,
                                                     const unsigned short* __restrict__ Wt1,
                                                     unsigned short* __restrict__ tbuf, int n,
                                                     int nGemm, int K) {
    int b = blockIdx.x;
    int g = b / K, r = b - g * K;
    if (r == 0 && g < nGemm) {
        gemm_body32<false>(h1, Wt1, nullptr, tbuf, n, g);
    } else {
        int sb = b - min(g + (r > 0 ? 1 : 0), nGemm);
        scatter_body(row, col, ewa, dinv, row_ptr, rank, edata, E, sb);
    }
}

// ---------- standalone GEMM (layers 2,3 messages): fp32 h -> bf16 msgs ----------
__global__ __launch_bounds__(256) void gemm_mfma_kernel(const float* __restrict__ A,
                                                        const unsigned short* __restrict__ Wt,
                                                        unsigned short* __restrict__ C, int n) {
    gemm_body32<true>(A, Wt, nullptr, C, n, blockIdx.x);
}

// ---------- scan phase 1: per-1024-chunk sums of PADDED counts (x8) ----------
__global__ __launch_bounds__(256) void scan1_kernel(const unsigned long long* __restrict__ packed,
                                                    int* __restrict__ bsum, int n) {
    __shared__ int s[256];
    int b = blockIdx.x, t = threadIdx.x;
    int base = b * 1024 + t * 4;
    int acc = 0;
#pragma unroll
    for (int i = 0; i < 4; ++i)
        if (base + i < n) acc += ((int)(packed[base + i] >> 40) + 7) & ~7;
    s[t] = acc;
    __syncthreads();
    for (int off = 128; off > 0; off >>= 1) {
        if (t < off) s[t] += s[t + off];
        __syncthreads();
    }
    if (t == 0) bsum[b] = s[0];
}

// ---------- scan phase 3 (phase 2 folded in): row_ptr + dinv + edata pad zeroing ----------
__global__ __launch_bounds__(256) void scan3_kernel(const unsigned long long* __restrict__ packed,
                                                    const int* __restrict__ bsum,
                                                    int* __restrict__ row_ptr,
                                                    float* __restrict__ dinv,
                                                    unsigned* __restrict__ edata,
                                                    int n, int nblk) {
    __shared__ int s[256];
    int b = blockIdx.x, t = threadIdx.x;

    int bv = (t < nblk) ? bsum[t] : 0;
    s[t] = bv;
    __syncthreads();
    for (int off = 1; off < 256; off <<= 1) {
        int u = (t >= off) ? s[t - off] : 0;
        __syncthreads();
        s[t] += u;
        __syncthreads();
    }
    int boffb = (b == 0) ? 0 : s[b - 1];
    int total = s[nblk - 1];
    __syncthreads();

    int base = b * 1024 + t * 4;
    int c[4], v[4];
#pragma unroll
    for (int i = 0; i < 4; ++i) {
        unsigned long long p = (base + i < n) ? packed[base + i] : 0ull;
        c[i] = (int)(p >> 40);
        v[i] = (c[i] + 7) & ~7;               // padded count
        if (base + i < n) {
            float deg = 1.0f + (float)(p & 0xFFFFFFFFFFull) * (1.0f / 16777216.0f);
            dinv[base + i] = rsqrtf(deg);
        }
    }
    s[t] = v[0] + v[1] + v[2] + v[3];
    __syncthreads();
    for (int off = 1; off < 256; off <<= 1) {
        int u = (t >= off) ? s[t - off] : 0;
        __syncthreads();
        s[t] += u;
        __syncthreads();
    }
    int run = boffb + ((t == 0) ? 0 : s[t - 1]);
#pragma unroll
    for (int i = 0; i < 4; ++i) {
        if (base + i < n) {
            row_ptr[base + i] = run;
            for (int z = c[i]; z < v[i]; ++z) edata[run + z] = 0;   // zero pad slots
            run += v[i];
        }
    }
    if (b == nblk - 1 && t == 255) row_ptr[n] = total;
}

// ---------- aggregation: one wave per dest node, edge-pair batched gather ----------
// Gathers bf16 messages; accumulates fp32; writes fp32 h (replay-safe) or sigmoid.
template<bool FINAL>
__global__ __launch_bounds__(256) void aggregate_kernel(const uint2* __restrict__ tb2,
                                                        const int* __restrict__ row_ptr,
                                                        const unsigned* __restrict__ edata,
                                                        const float* __restrict__ dinv,
                                                        const float* __restrict__ bias,
                                                        const float* __restrict__ W2,
                                                        const float* __restrict__ b2,
                                                        void* __restrict__ out, int n) {
    int wid  = (int)((blockIdx.x * (size_t)blockDim.x + threadIdx.x) >> 6);
    int lane = threadIdx.x & 63;
    if (wid >= n) return;
    int half = lane >> 5;     // which edge of each pair
    int fl   = lane & 31;     // feature group (4 feats)

    float a0 = 0.f, a1 = 0.f, a2 = 0.f, a3 = 0.f;

    int start = row_ptr[wid], end = row_ptr[wid + 1];
    for (int base = start; base < end; base += 64) {
        unsigned ed = edata[base + lane];     // over-read into next buckets is harmless
        int m = end - base; if (m > 64) m = 64;
        int j = 0;
        for (; j + 16 <= m; j += 16) {        // 8 pairs = 16 edges
            unsigned p[8]; uint2 u[8];
#pragma unroll
            for (int k = 0; k < 8; ++k) p[k] = __shfl(ed, j + 2 * k + half);
#pragma unroll
            for (int k = 0; k < 8; ++k) u[k] = tb2[(size_t)(p[k] >> 15) * 32 + fl];
#pragma unroll
            for (int k = 0; k < 8; ++k) {
                float w = __uint_as_float((p[k] & 0x7fffu) << 16);
                a0 += w * bf_lo(u[k].x); a1 += w * bf_hi(u[k].x);
                a2 += w * bf_lo(u[k].y); a3 += w * bf_hi(u[k].y);
            }
        }
        for (; j < m; j += 8) {               // 4 pairs = 8 edges (m is mult of 8)
            unsigned p[4]; uint2 u[4];
#pragma unroll
            for (int k = 0; k < 4; ++k) p[k] = __shfl(ed, j + 2 * k + half);
#pragma unroll
            for (int k = 0; k < 4; ++k) u[k] = tb2[(size_t)(p[k] >> 15) * 32 + fl];
#pragma unroll
            for (int k = 0; k < 4; ++k) {
                float w = __uint_as_float((p[k] & 0x7fffu) << 16);
                a0 += w * bf_lo(u[k].x); a1 += w * bf_hi(u[k].x);
                a2 += w * bf_lo(u[k].y); a3 += w * bf_hi(u[k].y);
            }
        }
    }
    // combine the two halves (lanes l and l^32 end up with identical sums)
    a0 += __shfl_xor(a0, 32); a1 += __shfl_xor(a1, 32);
    a2 += __shfl_xor(a2, 32); a3 += __shfl_xor(a3, 32);

    // self-loop + bias (mirrored across halves)
    float di = dinv[wid];
    float sn = di * di;
    uint2 ts = tb2[(size_t)wid * 32 + fl];
    a0 += sn * bf_lo(ts.x); a1 += sn * bf_hi(ts.x);
    a2 += sn * bf_lo(ts.y); a3 += sn * bf_hi(ts.y);
    float4 bb = ((const float4*)bias)[fl];
    a0 += bb.x; a1 += bb.y; a2 += bb.z; a3 += bb.w;

    if (FINAL) {
        float4 wv = ((const float4*)W2)[fl];
        float d = a0 * wv.x + a1 * wv.y + a2 * wv.z + a3 * wv.w;
        if (half) d = 0.f;                    // halves mirror: count once
#pragma unroll
        for (int off = 32; off > 0; off >>= 1) d += __shfl_xor(d, off);
        if (lane == 0) ((float*)out)[wid] = 1.0f / (1.0f + expf(-(d + b2[0])));
    } else if (half == 0) {
        float4 o; o.x = a0; o.y = a1; o.z = a2; o.w = a3;
        ((float4*)out)[(size_t)wid * 32 + fl] = o;   // fp32 h state
    }
}

static inline char* align16(char* p) { return (char*)(((uintptr_t)p + 15) & ~(uintptr_t)15); }

extern "C" void kernel_launch(void* const* d_in, const int* in_sizes, int n_in,
                              void* d_out, int out_size, void* d_ws, size_t ws_size,
                              hipStream_t stream) {
    const float* x  = (const float*)d_in[0];
    const int*   ei = (const int*)d_in[1];   // [2, E] int32
    const float* ea = (const float*)d_in[2]; // [E]
    const float* W1 = (const float*)d_in[3];
    const float* b1 = (const float*)d_in[4];
    const float* Wg = (const float*)d_in[5]; // [3,128,128]
    const float* bg = (const float*)d_in[6]; // [3,128]
    const float* W2 = (const float*)d_in[7]; // [128]
    const float* b2 = (const float*)d_in[8]; // [1]

    const int N = in_sizes[0] / 128;
    const int E = in_sizes[2];
    const int Npad = (N + 127) & ~127;
    const int* row = ei;
    const int* col = ei + E;

    // workspace layout
    char* p = (char*)d_ws;
    unsigned short* h1   = (unsigned short*)p; p += (size_t)Npad * 128 * 2;  // bf16 h1 (deterministic)
    float*          hbuf = (float*)p;          p += (size_t)Npad * 128 * 4;  // fp32 middle h
    unsigned short* tbuf = (unsigned short*)p; p += (size_t)Npad * 128 * 2;  // bf16 messages
    unsigned short* wbuf = (unsigned short*)p; p += 4 * 16384 * 2;           // bf16 W^T x4
    p = align16(p);
    unsigned long long* packed = (unsigned long long*)p; p += (size_t)N * 8;
    float* dinv   = (float*)p; p += (size_t)N * 4;
    int* row_ptr  = (int*)p;   p += (size_t)(N + 1) * 4; p = align16(p);
    int* bsum     = (int*)p;   p += 256 * 4;
    unsigned short* rank = (unsigned short*)p; p += (size_t)E * 2; p = align16(p);
    unsigned* edata = (unsigned*)p;                    // E + 7N + 64 padded records

    dim3 b256(256);
    int nblk  = (N + 1023) / 1024;          // 98 (<=256)
    int nGemm = Npad / 128;                 // 782
    int nHist = (E + 1023) / 1024;          // 1563 (4 edges/thread)
    int nScat = (E + 1023) / 1024;          // 1563
    int nPrep = (max(N, 65536) + 255) / 256;

    int gridA = nHist + nGemm;
    int KA    = (gridA + nGemm - 1) / nGemm;   // 3
    int gridE = nScat + nGemm;
    int KE    = (gridE + nGemm - 1) / nGemm;   // 3

    prep_kernel<<<nPrep, b256, 0, stream>>>(W1, Wg, wbuf, packed, N);
    fusedA_kernel<<<gridA, b256, 0, stream>>>(col, ea, packed, rank, E,
                                              x, wbuf, b1, h1, N, nGemm, KA);
    scan1_kernel <<<nblk, b256, 0, stream>>>(packed, bsum, N);
    scan3_kernel <<<nblk, b256, 0, stream>>>(packed, bsum, row_ptr, dinv, edata, N, nblk);
    fusedE_kernel<<<gridE, b256, 0, stream>>>(row, col, ea, dinv, row_ptr, rank, edata, E,
                                              h1, wbuf + 16384, tbuf, N, nGemm, KE);

    int wave_blocks = (int)(((size_t)N * 64 + 255) / 256);

    // agg0 -> hbuf(fp32); gemm(l=1) -> tbuf; agg1 -> hbuf; gemm(l=2) -> tbuf; agg2 -> out
    aggregate_kernel<false><<<wave_blocks, b256, 0, stream>>>(
        (const uint2*)tbuf, row_ptr, edata, dinv, bg, nullptr, nullptr, hbuf, N);
    gemm_mfma_kernel<<<nGemm, b256, 0, stream>>>(hbuf, wbuf + 2 * 16384, tbuf, N);
    aggregate_kernel<false><<<wave_blocks, b256, 0, stream>>>(
        (const uint2*)tbuf, row_ptr, edata, dinv, bg + 128, nullptr, nullptr, hbuf, N);
    gemm_mfma_kernel<<<nGemm, b256, 0, stream>>>(hbuf, wbuf + 3 * 16384, tbuf, N);
    aggregate_kernel<true><<<wave_blocks, b256, 0, stream>>>(
        (const uint2*)tbuf, row_ptr, edata, dinv, bg + 256, W2, b2, d_out, N);
}

// Round 11
// 446.457 us; speedup vs baseline: 1.1889x; 1.0993x over previous
//
#include <hip/hip_runtime.h>
#include <cstdint>
#include <cstddef>

// SimpleGCN: h = x@W1+b1; 3x GCNConv(sym-norm adj w/ self loops); sigmoid(h@W2+b2)
// N=100000, d=128, E=1.6M.
// R11: ALGEBRAIC COLLAPSE (aggregation commutes with right-multiplication):
//   front: t0 = x@(W1·Wg0) + b1·Wg0      -> gemm1 + h1 buffer eliminated
//   back:  out = sigmoid(A(h2·(Wg2·W2)) + (bg2·W2+b2))
//          -> layer-2's 410MB 128-dim gather becomes a 4B SCALAR gather from a
//             400KB L2-resident array; agg1 projects h2->s in-register (h2 never
//             materialized).
// Kept floors (measured R2-R10): histo 74us (22G/s device-atomic rate),
// agg 128-dim gather ~70us/layer (L2/fabric), atomic+MFMA don't co-schedule.
// Replay stability (R6 lesson): no bf16 re-quantization of atomic-order-
// dependent sums; h fp32, s fp32; only GEMM outputs go bf16 (deterministic).

typedef __attribute__((ext_vector_type(8))) short bf16x8;
typedef __attribute__((ext_vector_type(4))) float f32x4;

// ---------- bf16 helpers (packed dword: low 16 bits = element 0) ----------
__device__ __forceinline__ unsigned f2bf(float f) {      // RNE float->bf16 bits
    unsigned u = __float_as_uint(f);
    u += 0x7fffu + ((u >> 16) & 1u);
    return u >> 16;
}
__device__ __forceinline__ float bf_lo(unsigned p) { return __uint_as_float(p << 16); }
__device__ __forceinline__ float bf_hi(unsigned p) { return __uint_as_float(p & 0xffff0000u); }

// ---------- prep P1: Wt1 (Wg1^T bf16), wc2 = Wg2@W2, bc0 = b1@Wg0, c2, zero packed ----------
__global__ void prep1_kernel(const float* __restrict__ Wg, const float* __restrict__ b1,
                             const float* __restrict__ W2, const float* __restrict__ bg,
                             const float* __restrict__ b2,
                             unsigned short* __restrict__ Wt1, float* __restrict__ wc2,
                             float* __restrict__ bc0, float* __restrict__ c2,
                             unsigned long long* __restrict__ packed, int n) {
    int idx = blockIdx.x * blockDim.x + threadIdx.x;
    if (idx < 16384) {              // Wt1[n*128+k] = bf16(Wg1[k][n])
        int nn = idx >> 7, k = idx & 127;
        Wt1[idx] = (unsigned short)f2bf(Wg[16384 + k * 128 + nn]);
    }
    if (idx < 128) {                // wc2[k] = sum_n Wg2[k][n] * W2[n]
        float acc = 0.f;
        for (int j = 0; j < 128; ++j) acc += Wg[2 * 16384 + idx * 128 + j] * W2[j];
        wc2[idx] = acc;
    } else if (idx < 256) {         // bc0[n] = sum_j b1[j] * Wg0[j][n]
        int nn = idx - 128;
        float acc = 0.f;
        for (int j = 0; j < 128; ++j) acc += b1[j] * Wg[j * 128 + nn];
        bc0[nn] = acc;
    } else if (idx == 256) {        // c2 = bg2 . W2 + b2
        float acc = b2[0];
        for (int j = 0; j < 128; ++j) acc += bg[256 + j] * W2[j];
        c2[0] = acc;
    }
    if (idx < n) packed[idx] = 0ull;
}

// ---------- prep P2: Wt0[n*128+k] = bf16( (W1 @ Wg0)[k][n] ) ----------
__global__ void prep2_kernel(const float* __restrict__ W1, const float* __restrict__ Wg,
                             unsigned short* __restrict__ Wt0) {
    int idx = blockIdx.x * blockDim.x + threadIdx.x;   // 0..16383
    int nn = idx >> 7, k = idx & 127;
    float acc = 0.f;
    for (int j = 0; j < 128; ++j) acc += W1[k * 128 + j] * Wg[j * 128 + nn];
    Wt0[idx] = (unsigned short)f2bf(acc);
}

// ---------- GEMM body (32x128 wave tile): C(bf16) = A @ W (+bias fp32) ----------
// No LDS/barriers; Wt (bf16 W^T) is L1/L2-resident. A fp32, converted in-register.
__device__ __forceinline__ void gemm_body32(const float* __restrict__ A,
                                            const unsigned short* __restrict__ Wt,
                                            const float* __restrict__ bias,
                                            unsigned short* __restrict__ C, int n, int blk) {
    int tid = threadIdx.x;
    int wave = tid >> 6, lane = tid & 63;
    int lm = lane & 15, g = lane >> 4;
    int m_base = blk * 128 + wave * 32;

    f32x4 acc[2][8];
#pragma unroll
    for (int rt = 0; rt < 2; ++rt)
#pragma unroll
        for (int ct = 0; ct < 8; ++ct) acc[rt][ct] = (f32x4){0.f, 0.f, 0.f, 0.f};

    size_t rowA[2];
    rowA[0] = (size_t)min(m_base + lm, n - 1);
    rowA[1] = (size_t)min(m_base + 16 + lm, n - 1);

#pragma unroll
    for (int kc = 0; kc < 4; ++kc) {
        int k0 = kc * 32 + g * 8;
        bf16x8 a[2];
#pragma unroll
        for (int rt = 0; rt < 2; ++rt) {
            const float* p = A + rowA[rt] * 128 + k0;
            float f[8];
            *(float4*)&f[0] = *(const float4*)p;
            *(float4*)&f[4] = *(const float4*)(p + 4);
            short sv[8];
#pragma unroll
            for (int j = 0; j < 8; ++j) sv[j] = (short)f2bf(f[j]);
            a[rt] = *(bf16x8*)sv;
        }
        bf16x8 b[8];
#pragma unroll
        for (int ct = 0; ct < 8; ++ct)
            b[ct] = *(const bf16x8*)(Wt + (ct * 16 + lm) * 128 + k0);
#pragma unroll
        for (int ct = 0; ct < 8; ++ct) {
            acc[0][ct] = __builtin_amdgcn_mfma_f32_16x16x32_bf16(a[0], b[ct], acc[0][ct], 0, 0, 0);
            acc[1][ct] = __builtin_amdgcn_mfma_f32_16x16x32_bf16(a[1], b[ct], acc[1][ct], 0, 0, 0);
        }
    }

#pragma unroll
    for (int rt = 0; rt < 2; ++rt) {
#pragma unroll
        for (int r = 0; r < 4; ++r) {
            int grow = m_base + rt * 16 + g * 4 + r;
            if (grow < n) {
#pragma unroll
                for (int ct = 0; ct < 8; ++ct) {
                    float v = acc[rt][ct][r];
                    if (bias) v += bias[ct * 16 + lm];
                    C[(size_t)grow * 128 + ct * 16 + lm] = (unsigned short)f2bf(v);
                }
            }
        }
    }
}

// ---------- histo: 4 edges/thread, 1 u64 atomic each; rank = returned count ----------
__global__ __launch_bounds__(256) void histo_kernel(const int* __restrict__ col,
                                                    const float* __restrict__ ewa,
                                                    unsigned long long* __restrict__ packed,
                                                    unsigned short* __restrict__ rank, int E) {
    int e0 = (blockIdx.x * 256 + threadIdx.x) * 4;
    if (e0 + 3 < E) {
        int4   c4 = *(const int4*)(col + e0);
        float4 w4 = *(const float4*)(ewa + e0);
        int   c[4] = {c4.x, c4.y, c4.z, c4.w};
        float w[4] = {w4.x, w4.y, w4.z, w4.w};
        unsigned short rk[4];
#pragma unroll
        for (int i = 0; i < 4; ++i) {
            unsigned long long v = (1ull << 40) |
                (unsigned long long)(unsigned)(w[i] * 16777216.0f);
            unsigned long long old = atomicAdd(&packed[c[i]], v);
            rk[i] = (unsigned short)(old >> 40);
        }
        *(ushort4*)(rank + e0) = make_ushort4(rk[0], rk[1], rk[2], rk[3]);
    } else {
        for (int e = e0; e < E; ++e) {
            unsigned long long v = (1ull << 40) |
                (unsigned long long)(unsigned)(ewa[e] * 16777216.0f);
            unsigned long long old = atomicAdd(&packed[col[e]], v);
            rank[e] = (unsigned short)(old >> 40);
        }
    }
}

// ---------- scatter body (NO atomics): pos = row_ptr[c] + rank[e], 4 edges/thread ----------
// record = (src << 15) | (bf16(norm) & 0x7fff); norm > 0 so sign bit unused.
__device__ __forceinline__ void scatter_body(const int* __restrict__ row, const int* __restrict__ col,
                                             const float* __restrict__ ew, const float* __restrict__ dinv,
                                             const int* __restrict__ row_ptr,
                                             const unsigned short* __restrict__ rank,
                                             unsigned* __restrict__ edata, int E, int blk) {
    int e0 = (blk * 256 + threadIdx.x) * 4;
    if (e0 + 3 < E) {
        int4   r4 = *(const int4*)(row + e0);
        int4   c4 = *(const int4*)(col + e0);
        float4 w4 = *(const float4*)(ew + e0);
        ushort4 k4 = *(const ushort4*)(rank + e0);
        int   r[4] = {r4.x, r4.y, r4.z, r4.w};
        int   c[4] = {c4.x, c4.y, c4.z, c4.w};
        float w[4] = {w4.x, w4.y, w4.z, w4.w};
        unsigned short kk[4] = {k4.x, k4.y, k4.z, k4.w};
#pragma unroll
        for (int i = 0; i < 4; ++i) {
            float nrm = dinv[r[i]] * w[i] * dinv[c[i]];
            int pos = row_ptr[c[i]] + (int)kk[i];
            edata[pos] = ((unsigned)r[i] << 15) | (f2bf(nrm) & 0x7fffu);
        }
    } else {
        for (int e = e0; e < E; ++e) {
            int r = row[e], c = col[e];
            float nrm = dinv[r] * ew[e] * dinv[c];
            int pos = row_ptr[c] + (int)rank[e];
            edata[pos] = ((unsigned)r << 15) | (f2bf(nrm) & 0x7fffu);
        }
    }
}

// ---------- fused E: scatter || gemmC0 (x@Wc0 + bc0 -> tbuf bf16) ----------
__global__ __launch_bounds__(256) void fusedE_kernel(const int* __restrict__ row,
                                                     const int* __restrict__ col,
                                                     const float* __restrict__ ewa,
                                                     const float* __restrict__ dinv,
                                                     const int* __restrict__ row_ptr,
                                                     const unsigned short* __restrict__ rank,
                                                     unsigned* __restrict__ edata, int E,
                                                     const float* __restrict__ x,
                                                     const unsigned short* __restrict__ Wt0,
                                                     const float* __restrict__ bc0,
                                                     unsigned short* __restrict__ tbuf, int n,
                                                     int nGemm, int K) {
    int b = blockIdx.x;
    int g = b / K, r = b - g * K;
    if (r == 0 && g < nGemm) {
        gemm_body32(x, Wt0, bc0, tbuf, n, g);
    } else {
        int sb = b - min(g + (r > 0 ? 1 : 0), nGemm);
        scatter_body(row, col, ewa, dinv, row_ptr, rank, edata, E, sb);
    }
}

// ---------- standalone GEMM (layer-1 messages): fp32 h @ Wt1 -> bf16 msgs ----------
__global__ __launch_bounds__(256) void gemm_mfma_kernel(const float* __restrict__ A,
                                                        const unsigned short* __restrict__ Wt,
                                                        unsigned short* __restrict__ C, int n) {
    gemm_body32(A, Wt, nullptr, C, n, blockIdx.x);
}

// ---------- scan phase 1: per-1024-chunk sums of PADDED counts (x8) ----------
__global__ __launch_bounds__(256) void scan1_kernel(const unsigned long long* __restrict__ packed,
                                                    int* __restrict__ bsum, int n) {
    __shared__ int s[256];
    int b = blockIdx.x, t = threadIdx.x;
    int base = b * 1024 + t * 4;
    int acc = 0;
#pragma unroll
    for (int i = 0; i < 4; ++i)
        if (base + i < n) acc += ((int)(packed[base + i] >> 40) + 7) & ~7;
    s[t] = acc;
    __syncthreads();
    for (int off = 128; off > 0; off >>= 1) {
        if (t < off) s[t] += s[t + off];
        __syncthreads();
    }
    if (t == 0) bsum[b] = s[0];
}

// ---------- scan phase 3 (phase 2 folded): row_ptr + dinv + edata pad zeroing ----------
__global__ __launch_bounds__(256) void scan3_kernel(const unsigned long long* __restrict__ packed,
                                                    const int* __restrict__ bsum,
                                                    int* __restrict__ row_ptr,
                                                    float* __restrict__ dinv,
                                                    unsigned* __restrict__ edata,
                                                    int n, int nblk) {
    __shared__ int s[256];
    int b = blockIdx.x, t = threadIdx.x;

    int bv = (t < nblk) ? bsum[t] : 0;
    s[t] = bv;
    __syncthreads();
    for (int off = 1; off < 256; off <<= 1) {
        int u = (t >= off) ? s[t - off] : 0;
        __syncthreads();
        s[t] += u;
        __syncthreads();
    }
    int boffb = (b == 0) ? 0 : s[b - 1];
    int total = s[nblk - 1];
    __syncthreads();

    int base = b * 1024 + t * 4;
    int c[4], v[4];
#pragma unroll
    for (int i = 0; i < 4; ++i) {
        unsigned long long p = (base + i < n) ? packed[base + i] : 0ull;
        c[i] = (int)(p >> 40);
        v[i] = (c[i] + 7) & ~7;               // padded count
        if (base + i < n) {
            float deg = 1.0f + (float)(p & 0xFFFFFFFFFFull) * (1.0f / 16777216.0f);
            dinv[base + i] = rsqrtf(deg);
        }
    }
    s[t] = v[0] + v[1] + v[2] + v[3];
    __syncthreads();
    for (int off = 1; off < 256; off <<= 1) {
        int u = (t >= off) ? s[t - off] : 0;
        __syncthreads();
        s[t] += u;
        __syncthreads();
    }
    int run = boffb + ((t == 0) ? 0 : s[t - 1]);
#pragma unroll
    for (int i = 0; i < 4; ++i) {
        if (base + i < n) {
            row_ptr[base + i] = run;
            for (int z = c[i]; z < v[i]; ++z) edata[run + z] = 0;   // zero pad slots
            run += v[i];
        }
    }
    if (b == nblk - 1 && t == 255) row_ptr[n] = total;
}

// ---------- aggregation: one wave per dest node, edge-pair batched gather ----------
// PROJECT=false: write fp32 h row. PROJECT=true: write s[wid] = h_row . wc2 (fp32).
template<bool PROJECT>
__global__ __launch_bounds__(256) void aggregate_kernel(const uint2* __restrict__ tb2,
                                                        const int* __restrict__ row_ptr,
                                                        const unsigned* __restrict__ edata,
                                                        const float* __restrict__ dinv,
                                                        const float* __restrict__ bias,
                                                        const float* __restrict__ wc2,
                                                        void* __restrict__ out, int n) {
    int wid  = (int)((blockIdx.x * (size_t)blockDim.x + threadIdx.x) >> 6);
    int lane = threadIdx.x & 63;
    if (wid >= n) return;
    int half = lane >> 5;     // which edge of each pair
    int fl   = lane & 31;     // feature group (4 feats)

    float a0 = 0.f, a1 = 0.f, a2 = 0.f, a3 = 0.f;

    int start = row_ptr[wid], end = row_ptr[wid + 1];
    for (int base = start; base < end; base += 64) {
        unsigned ed = edata[base + lane];     // over-read into next buckets is harmless
        int m = end - base; if (m > 64) m = 64;
        int j = 0;
        for (; j + 16 <= m; j += 16) {        // 8 pairs = 16 edges
            unsigned p[8]; uint2 u[8];
#pragma unroll
            for (int k = 0; k < 8; ++k) p[k] = __shfl(ed, j + 2 * k + half);
#pragma unroll
            for (int k = 0; k < 8; ++k) u[k] = tb2[(size_t)(p[k] >> 15) * 32 + fl];
#pragma unroll
            for (int k = 0; k < 8; ++k) {
                float w = __uint_as_float((p[k] & 0x7fffu) << 16);
                a0 += w * bf_lo(u[k].x); a1 += w * bf_hi(u[k].x);
                a2 += w * bf_lo(u[k].y); a3 += w * bf_hi(u[k].y);
            }
        }
        for (; j < m; j += 8) {               // 4 pairs = 8 edges (m is mult of 8)
            unsigned p[4]; uint2 u[4];
#pragma unroll
            for (int k = 0; k < 4; ++k) p[k] = __shfl(ed, j + 2 * k + half);
#pragma unroll
            for (int k = 0; k < 4; ++k) u[k] = tb2[(size_t)(p[k] >> 15) * 32 + fl];
#pragma unroll
            for (int k = 0; k < 4; ++k) {
                float w = __uint_as_float((p[k] & 0x7fffu) << 16);
                a0 += w * bf_lo(u[k].x); a1 += w * bf_hi(u[k].x);
                a2 += w * bf_lo(u[k].y); a3 += w * bf_hi(u[k].y);
            }
        }
    }
    // combine the two halves (lanes l and l^32 end up with identical sums)
    a0 += __shfl_xor(a0, 32); a1 += __shfl_xor(a1, 32);
    a2 += __shfl_xor(a2, 32); a3 += __shfl_xor(a3, 32);

    // self-loop + bias (mirrored across halves)
    float di = dinv[wid];
    float sn = di * di;
    uint2 ts = tb2[(size_t)wid * 32 + fl];
    a0 += sn * bf_lo(ts.x); a1 += sn * bf_hi(ts.x);
    a2 += sn * bf_lo(ts.y); a3 += sn * bf_hi(ts.y);
    float4 bb = ((const float4*)bias)[fl];
    a0 += bb.x; a1 += bb.y; a2 += bb.z; a3 += bb.w;

    if (PROJECT) {
        float4 wv = ((const float4*)wc2)[fl];
        float d = a0 * wv.x + a1 * wv.y + a2 * wv.z + a3 * wv.w;
        if (half) d = 0.f;                    // halves mirror: count once
#pragma unroll
        for (int off = 32; off > 0; off >>= 1) d += __shfl_xor(d, off);
        if (lane == 0) ((float*)out)[wid] = d;     // s[wid], fp32
    } else if (half == 0) {
        float4 o; o.x = a0; o.y = a1; o.z = a2; o.w = a3;
        ((float4*)out)[(size_t)wid * 32 + fl] = o; // fp32 h state
    }
}

// ---------- final: scalar gather  out[i] = sigmoid( A s + c2 ) ----------
__global__ __launch_bounds__(256) void aggFinal_kernel(const float* __restrict__ s,
                                                       const int* __restrict__ row_ptr,
                                                       const unsigned* __restrict__ edata,
                                                       const float* __restrict__ dinv,
                                                       const float* __restrict__ c2,
                                                       float* __restrict__ out, int n) {
    int wid  = (int)((blockIdx.x * (size_t)blockDim.x + threadIdx.x) >> 6);
    int lane = threadIdx.x & 63;
    if (wid >= n) return;
    int start = row_ptr[wid], end = row_ptr[wid + 1];
    float acc = 0.f;
    for (int base = start; base < end; base += 64) {
        int idx = base + lane;
        if (idx < end) {                      // pads have norm=0 -> harmless
            unsigned ed = edata[idx];
            float w = __uint_as_float((ed & 0x7fffu) << 16);
            acc += w * s[ed >> 15];
        }
    }
#pragma unroll
    for (int off = 32; off > 0; off >>= 1) acc += __shfl_xor(acc, off);
    if (lane == 0) {
        float di = dinv[wid];
        float d = acc + di * di * s[wid] + c2[0];
        out[wid] = 1.0f / (1.0f + expf(-d));
    }
}

static inline char* align16(char* p) { return (char*)(((uintptr_t)p + 15) & ~(uintptr_t)15); }

extern "C" void kernel_launch(void* const* d_in, const int* in_sizes, int n_in,
                              void* d_out, int out_size, void* d_ws, size_t ws_size,
                              hipStream_t stream) {
    const float* x  = (const float*)d_in[0];
    const int*   ei = (const int*)d_in[1];   // [2, E] int32
    const float* ea = (const float*)d_in[2]; // [E]
    const float* W1 = (const float*)d_in[3];
    const float* b1 = (const float*)d_in[4];
    const float* Wg = (const float*)d_in[5]; // [3,128,128]
    const float* bg = (const float*)d_in[6]; // [3,128]
    const float* W2 = (const float*)d_in[7]; // [128]
    const float* b2 = (const float*)d_in[8]; // [1]

    const int N = in_sizes[0] / 128;
    const int E = in_sizes[2];
    const int Npad = (N + 127) & ~127;
    const int* row = ei;
    const int* col = ei + E;

    // workspace layout
    char* p = (char*)d_ws;
    float*          hbuf = (float*)p;          p += (size_t)Npad * 128 * 4;  // fp32 h state
    unsigned short* tbuf = (unsigned short*)p; p += (size_t)Npad * 128 * 2;  // bf16 messages
    unsigned short* wbuf = (unsigned short*)p; p += 2 * 16384 * 2;           // Wt0(=Wc0^T), Wt1
    float* bc0 = (float*)p;  p += 128 * 4;
    float* wc2 = (float*)p;  p += 128 * 4;
    float* c2  = (float*)p;  p += 16;
    float* sbuf = (float*)p; p += (size_t)N * 4;
    p = align16(p);
    unsigned long long* packed = (unsigned long long*)p; p += (size_t)N * 8;
    float* dinv   = (float*)p; p += (size_t)N * 4;
    int* row_ptr  = (int*)p;   p += (size_t)(N + 1) * 4; p = align16(p);
    int* bsum     = (int*)p;   p += 256 * 4;
    unsigned short* rank = (unsigned short*)p; p += (size_t)E * 2; p = align16(p);
    unsigned* edata = (unsigned*)p;                    // E + 7N + 64 padded records

    dim3 b256(256);
    int nblk  = (N + 1023) / 1024;          // 98 (<=256)
    int nGemm = Npad / 128;                 // 782
    int nHist = (E + 1023) / 1024;          // 1563 (4 edges/thread)
    int nScat = (E + 1023) / 1024;          // 1563
    int nPrep = (max(N, 16384) + 255) / 256;

    int gridE = nScat + nGemm;
    int KE    = (gridE + nGemm - 1) / nGemm;   // 3

    prep1_kernel<<<nPrep, b256, 0, stream>>>(Wg, b1, W2, bg, b2, wbuf + 16384,
                                             wc2, bc0, c2, packed, N);
    prep2_kernel<<<64, b256, 0, stream>>>(W1, Wg, wbuf);
    histo_kernel<<<nHist, b256, 0, stream>>>(col, ea, packed, rank, E);
    scan1_kernel<<<nblk, b256, 0, stream>>>(packed, bsum, N);
    scan3_kernel<<<nblk, b256, 0, stream>>>(packed, bsum, row_ptr, dinv, edata, N, nblk);
    fusedE_kernel<<<gridE, b256, 0, stream>>>(row, col, ea, dinv, row_ptr, rank, edata, E,
                                              x, wbuf, bc0, tbuf, N, nGemm, KE);

    int wave_blocks = (int)(((size_t)N * 64 + 255) / 256);

    // agg0 -> hbuf(fp32); gemm(Wg1) -> tbuf; agg1+project -> sbuf; final scalar gather
    aggregate_kernel<false><<<wave_blocks, b256, 0, stream>>>(
        (const uint2*)tbuf, row_ptr, edata, dinv, bg, nullptr, hbuf, N);
    gemm_mfma_kernel<<<nGemm, b256, 0, stream>>>(hbuf, wbuf + 16384, tbuf, N);
    aggregate_kernel<true><<<wave_blocks, b256, 0, stream>>>(
        (const uint2*)tbuf, row_ptr, edata, dinv, bg + 128, wc2, sbuf, N);
    aggFinal_kernel<<<wave_blocks, b256, 0, stream>>>(sbuf, row_ptr, edata, dinv, c2,
                                                      (float*)d_out, N);
}

// Round 12
// 410.584 us; speedup vs baseline: 1.2927x; 1.0874x over previous
//
#include <hip/hip_runtime.h>
#include <cstdint>
#include <cstddef>

// SimpleGCN: h = x@W1+b1; 3x GCNConv(sym-norm adj w/ self loops); sigmoid(h@W2+b2)
// N=100000, d=128, E=1.6M.
// R12 = R11 (algebraic collapse) + launch-pairing fix:
//   R11's fusedE (scatter||gemm) ran at 87us: gemm's VGPR=88 capped occupancy
//   at 16%, starving the LATENCY-bound scatter (unlike histo, which is
//   atomic-RATE-bound and occupancy-insensitive -- R8). New pairing:
//     fusedA = histo || gemmC0 (both dependency-free; ~= R10's measured 93us)
//     scatter standalone at full occupancy (~30us)
//   prep2 folded into prep1. 9 dispatches total.
// Algebra (R11): Wc0 = W1@Wg0 (front collapse), wc2 = Wg2@W2, c2 = bg2.W2+b2
//   (back collapse: layer-2 gather is a 4B scalar gather from L2-resident s[]).
// Floors (measured): histo 74us (22G/s atomics), 128-dim gather ~70us/layer.
// Replay stability (R6): no bf16 re-quantization of atomic-order-dependent
// sums -- h and s stay fp32; only deterministic GEMM outputs go bf16.

typedef __attribute__((ext_vector_type(8))) short bf16x8;
typedef __attribute__((ext_vector_type(4))) float f32x4;

// ---------- bf16 helpers (packed dword: low 16 bits = element 0) ----------
__device__ __forceinline__ unsigned f2bf(float f) {      // RNE float->bf16 bits
    unsigned u = __float_as_uint(f);
    u += 0x7fffu + ((u >> 16) & 1u);
    return u >> 16;
}
__device__ __forceinline__ float bf_lo(unsigned p) { return __uint_as_float(p << 16); }
__device__ __forceinline__ float bf_hi(unsigned p) { return __uint_as_float(p & 0xffff0000u); }

// ---------- prep (merged): Wt0 = (W1@Wg0)^T bf16, Wt1 = Wg1^T bf16,
//            wc2 = Wg2@W2, bc0 = b1@Wg0, c2 = bg2.W2+b2, zero packed ----------
__global__ void prep_kernel(const float* __restrict__ W1, const float* __restrict__ Wg,
                            const float* __restrict__ b1, const float* __restrict__ W2,
                            const float* __restrict__ bg, const float* __restrict__ b2,
                            unsigned short* __restrict__ Wt0, unsigned short* __restrict__ Wt1,
                            float* __restrict__ wc2, float* __restrict__ bc0,
                            float* __restrict__ c2,
                            unsigned long long* __restrict__ packed, int n) {
    int idx = blockIdx.x * blockDim.x + threadIdx.x;
    if (idx < 16384) {              // Wt0[nn*128+k] = bf16((W1@Wg0)[k][nn])
        int nn = idx >> 7, k = idx & 127;
        float acc = 0.f;
        for (int j = 0; j < 128; ++j) acc += W1[k * 128 + j] * Wg[j * 128 + nn];
        Wt0[idx] = (unsigned short)f2bf(acc);
    } else if (idx < 32768) {       // Wt1[nn*128+k] = bf16(Wg1[k][nn])
        int t = idx - 16384;
        int nn = t >> 7, k = t & 127;
        Wt1[t] = (unsigned short)f2bf(Wg[16384 + k * 128 + nn]);
    } else if (idx < 32896) {       // wc2[k] = sum_j Wg2[k][j] * W2[j]
        int k = idx - 32768;
        float acc = 0.f;
        for (int j = 0; j < 128; ++j) acc += Wg[2 * 16384 + k * 128 + j] * W2[j];
        wc2[k] = acc;
    } else if (idx < 33024) {       // bc0[nn] = sum_j b1[j] * Wg0[j][nn]
        int nn = idx - 32896;
        float acc = 0.f;
        for (int j = 0; j < 128; ++j) acc += b1[j] * Wg[j * 128 + nn];
        bc0[nn] = acc;
    } else if (idx == 33024) {      // c2 = bg2 . W2 + b2
        float acc = b2[0];
        for (int j = 0; j < 128; ++j) acc += bg[256 + j] * W2[j];
        c2[0] = acc;
    }
    if (idx < n) packed[idx] = 0ull;
}

// ---------- GEMM body (32x128 wave tile): C(bf16) = A(fp32) @ W (+bias) ----------
// No LDS/barriers; Wt (bf16 W^T) is L1/L2-resident; A converted in-register.
__device__ __forceinline__ void gemm_body32(const float* __restrict__ A,
                                            const unsigned short* __restrict__ Wt,
                                            const float* __restrict__ bias,
                                            unsigned short* __restrict__ C, int n, int blk) {
    int tid = threadIdx.x;
    int wave = tid >> 6, lane = tid & 63;
    int lm = lane & 15, g = lane >> 4;
    int m_base = blk * 128 + wave * 32;

    f32x4 acc[2][8];
#pragma unroll
    for (int rt = 0; rt < 2; ++rt)
#pragma unroll
        for (int ct = 0; ct < 8; ++ct) acc[rt][ct] = (f32x4){0.f, 0.f, 0.f, 0.f};

    size_t rowA[2];
    rowA[0] = (size_t)min(m_base + lm, n - 1);
    rowA[1] = (size_t)min(m_base + 16 + lm, n - 1);

#pragma unroll
    for (int kc = 0; kc < 4; ++kc) {
        int k0 = kc * 32 + g * 8;
        bf16x8 a[2];
#pragma unroll
        for (int rt = 0; rt < 2; ++rt) {
            const float* p = A + rowA[rt] * 128 + k0;
            float f[8];
            *(float4*)&f[0] = *(const float4*)p;
            *(float4*)&f[4] = *(const float4*)(p + 4);
            short sv[8];
#pragma unroll
            for (int j = 0; j < 8; ++j) sv[j] = (short)f2bf(f[j]);
            a[rt] = *(bf16x8*)sv;
        }
        bf16x8 b[8];
#pragma unroll
        for (int ct = 0; ct < 8; ++ct)
            b[ct] = *(const bf16x8*)(Wt + (ct * 16 + lm) * 128 + k0);
#pragma unroll
        for (int ct = 0; ct < 8; ++ct) {
            acc[0][ct] = __builtin_amdgcn_mfma_f32_16x16x32_bf16(a[0], b[ct], acc[0][ct], 0, 0, 0);
            acc[1][ct] = __builtin_amdgcn_mfma_f32_16x16x32_bf16(a[1], b[ct], acc[1][ct], 0, 0, 0);
        }
    }

#pragma unroll
    for (int rt = 0; rt < 2; ++rt) {
#pragma unroll
        for (int r = 0; r < 4; ++r) {
            int grow = m_base + rt * 16 + g * 4 + r;
            if (grow < n) {
#pragma unroll
                for (int ct = 0; ct < 8; ++ct) {
                    float v = acc[rt][ct][r];
                    if (bias) v += bias[ct * 16 + lm];
                    C[(size_t)grow * 128 + ct * 16 + lm] = (unsigned short)f2bf(v);
                }
            }
        }
    }
}

// ---------- fused A: histo (4 edges/thread, u64 atomic, rank) || gemmC0 ----------
// gemm blocks are b % K == 0 (b/K < nGemm); the rest are histo blocks.
__global__ __launch_bounds__(256) void fusedA_kernel(const int* __restrict__ col,
                                                     const float* __restrict__ ewa,
                                                     unsigned long long* __restrict__ packed,
                                                     unsigned short* __restrict__ rank, int E,
                                                     const float* __restrict__ x,
                                                     const unsigned short* __restrict__ Wt0,
                                                     const float* __restrict__ bc0,
                                                     unsigned short* __restrict__ tbuf, int n,
                                                     int nGemm, int K) {
    int b = blockIdx.x;
    int g = b / K, r = b - g * K;
    if (r == 0 && g < nGemm) {
        gemm_body32(x, Wt0, bc0, tbuf, n, g);
    } else {
        int hb = b - min(g + (r > 0 ? 1 : 0), nGemm);
        int e0 = (hb * 256 + threadIdx.x) * 4;
        if (e0 + 3 < E) {
            int4   c4 = *(const int4*)(col + e0);
            float4 w4 = *(const float4*)(ewa + e0);
            int   c[4] = {c4.x, c4.y, c4.z, c4.w};
            float w[4] = {w4.x, w4.y, w4.z, w4.w};
            unsigned short rk[4];
#pragma unroll
            for (int i = 0; i < 4; ++i) {
                unsigned long long v = (1ull << 40) |
                    (unsigned long long)(unsigned)(w[i] * 16777216.0f);
                unsigned long long old = atomicAdd(&packed[c[i]], v);
                rk[i] = (unsigned short)(old >> 40);
            }
            *(ushort4*)(rank + e0) = make_ushort4(rk[0], rk[1], rk[2], rk[3]);
        } else {
            for (int e = e0; e < E; ++e) {
                unsigned long long v = (1ull << 40) |
                    (unsigned long long)(unsigned)(ewa[e] * 16777216.0f);
                unsigned long long old = atomicAdd(&packed[col[e]], v);
                rank[e] = (unsigned short)(old >> 40);
            }
        }
    }
}

// ---------- scatter standalone (NO atomics, full occupancy): 4 edges/thread ----------
// record = (src << 15) | (bf16(norm) & 0x7fff); norm > 0 so sign bit unused.
__global__ __launch_bounds__(256) void scatter_kernel(const int* __restrict__ row,
                                                      const int* __restrict__ col,
                                                      const float* __restrict__ ew,
                                                      const float* __restrict__ dinv,
                                                      const int* __restrict__ row_ptr,
                                                      const unsigned short* __restrict__ rank,
                                                      unsigned* __restrict__ edata, int E) {
    int e0 = (blockIdx.x * 256 + threadIdx.x) * 4;
    if (e0 + 3 < E) {
        int4   r4 = *(const int4*)(row + e0);
        int4   c4 = *(const int4*)(col + e0);
        float4 w4 = *(const float4*)(ew + e0);
        ushort4 k4 = *(const ushort4*)(rank + e0);
        int   r[4] = {r4.x, r4.y, r4.z, r4.w};
        int   c[4] = {c4.x, c4.y, c4.z, c4.w};
        float w[4] = {w4.x, w4.y, w4.z, w4.w};
        unsigned short kk[4] = {k4.x, k4.y, k4.z, k4.w};
#pragma unroll
        for (int i = 0; i < 4; ++i) {
            float nrm = dinv[r[i]] * w[i] * dinv[c[i]];
            int pos = row_ptr[c[i]] + (int)kk[i];
            edata[pos] = ((unsigned)r[i] << 15) | (f2bf(nrm) & 0x7fffu);
        }
    } else {
        for (int e = e0; e < E; ++e) {
            int r = row[e], c = col[e];
            float nrm = dinv[r] * ew[e] * dinv[c];
            int pos = row_ptr[c] + (int)rank[e];
            edata[pos] = ((unsigned)r << 15) | (f2bf(nrm) & 0x7fffu);
        }
    }
}

// ---------- standalone GEMM (layer-1 messages): fp32 h @ Wt1 -> bf16 msgs ----------
__global__ __launch_bounds__(256) void gemm_mfma_kernel(const float* __restrict__ A,
                                                        const unsigned short* __restrict__ Wt,
                                                        unsigned short* __restrict__ C, int n) {
    gemm_body32(A, Wt, nullptr, C, n, blockIdx.x);
}

// ---------- scan phase 1: per-1024-chunk sums of PADDED counts (x8) ----------
__global__ __launch_bounds__(256) void scan1_kernel(const unsigned long long* __restrict__ packed,
                                                    int* __restrict__ bsum, int n) {
    __shared__ int s[256];
    int b = blockIdx.x, t = threadIdx.x;
    int base = b * 1024 + t * 4;
    int acc = 0;
#pragma unroll
    for (int i = 0; i < 4; ++i)
        if (base + i < n) acc += ((int)(packed[base + i] >> 40) + 7) & ~7;
    s[t] = acc;
    __syncthreads();
    for (int off = 128; off > 0; off >>= 1) {
        if (t < off) s[t] += s[t + off];
        __syncthreads();
    }
    if (t == 0) bsum[b] = s[0];
}

// ---------- scan phase 3 (phase 2 folded): row_ptr + dinv + edata pad zeroing ----------
__global__ __launch_bounds__(256) void scan3_kernel(const unsigned long long* __restrict__ packed,
                                                    const int* __restrict__ bsum,
                                                    int* __restrict__ row_ptr,
                                                    float* __restrict__ dinv,
                                                    unsigned* __restrict__ edata,
                                                    int n, int nblk) {
    __shared__ int s[256];
    int b = blockIdx.x, t = threadIdx.x;

    int bv = (t < nblk) ? bsum[t] : 0;
    s[t] = bv;
    __syncthreads();
    for (int off = 1; off < 256; off <<= 1) {
        int u = (t >= off) ? s[t - off] : 0;
        __syncthreads();
        s[t] += u;
        __syncthreads();
    }
    int boffb = (b == 0) ? 0 : s[b - 1];
    int total = s[nblk - 1];
    __syncthreads();

    int base = b * 1024 + t * 4;
    int c[4], v[4];
#pragma unroll
    for (int i = 0; i < 4; ++i) {
        unsigned long long p = (base + i < n) ? packed[base + i] : 0ull;
        c[i] = (int)(p >> 40);
        v[i] = (c[i] + 7) & ~7;               // padded count
        if (base + i < n) {
            float deg = 1.0f + (float)(p & 0xFFFFFFFFFFull) * (1.0f / 16777216.0f);
            dinv[base + i] = rsqrtf(deg);
        }
    }
    s[t] = v[0] + v[1] + v[2] + v[3];
    __syncthreads();
    for (int off = 1; off < 256; off <<= 1) {
        int u = (t >= off) ? s[t - off] : 0;
        __syncthreads();
        s[t] += u;
        __syncthreads();
    }
    int run = boffb + ((t == 0) ? 0 : s[t - 1]);
#pragma unroll
    for (int i = 0; i < 4; ++i) {
        if (base + i < n) {
            row_ptr[base + i] = run;
            for (int z = c[i]; z < v[i]; ++z) edata[run + z] = 0;   // zero pad slots
            run += v[i];
        }
    }
    if (b == nblk - 1 && t == 255) row_ptr[n] = total;
}

// ---------- aggregation: one wave per dest node, edge-pair batched gather ----------
// PROJECT=false: write fp32 h row. PROJECT=true: write s[wid] = h_row . wc2 (fp32).
template<bool PROJECT>
__global__ __launch_bounds__(256) void aggregate_kernel(const uint2* __restrict__ tb2,
                                                        const int* __restrict__ row_ptr,
                                                        const unsigned* __restrict__ edata,
                                                        const float* __restrict__ dinv,
                                                        const float* __restrict__ bias,
                                                        const float* __restrict__ wc2,
                                                        void* __restrict__ out, int n) {
    int wid  = (int)((blockIdx.x * (size_t)blockDim.x + threadIdx.x) >> 6);
    int lane = threadIdx.x & 63;
    if (wid >= n) return;
    int half = lane >> 5;     // which edge of each pair
    int fl   = lane & 31;     // feature group (4 feats)

    float a0 = 0.f, a1 = 0.f, a2 = 0.f, a3 = 0.f;

    int start = row_ptr[wid], end = row_ptr[wid + 1];
    for (int base = start; base < end; base += 64) {
        unsigned ed = edata[base + lane];     // over-read into next buckets is harmless
        int m = end - base; if (m > 64) m = 64;
        int j = 0;
        for (; j + 16 <= m; j += 16) {        // 8 pairs = 16 edges
            unsigned p[8]; uint2 u[8];
#pragma unroll
            for (int k = 0; k < 8; ++k) p[k] = __shfl(ed, j + 2 * k + half);
#pragma unroll
            for (int k = 0; k < 8; ++k) u[k] = tb2[(size_t)(p[k] >> 15) * 32 + fl];
#pragma unroll
            for (int k = 0; k < 8; ++k) {
                float w = __uint_as_float((p[k] & 0x7fffu) << 16);
                a0 += w * bf_lo(u[k].x); a1 += w * bf_hi(u[k].x);
                a2 += w * bf_lo(u[k].y); a3 += w * bf_hi(u[k].y);
            }
        }
        for (; j < m; j += 8) {               // 4 pairs = 8 edges (m is mult of 8)
            unsigned p[4]; uint2 u[4];
#pragma unroll
            for (int k = 0; k < 4; ++k) p[k] = __shfl(ed, j + 2 * k + half);
#pragma unroll
            for (int k = 0; k < 4; ++k) u[k] = tb2[(size_t)(p[k] >> 15) * 32 + fl];
#pragma unroll
            for (int k = 0; k < 4; ++k) {
                float w = __uint_as_float((p[k] & 0x7fffu) << 16);
                a0 += w * bf_lo(u[k].x); a1 += w * bf_hi(u[k].x);
                a2 += w * bf_lo(u[k].y); a3 += w * bf_hi(u[k].y);
            }
        }
    }
    // combine the two halves (lanes l and l^32 end up with identical sums)
    a0 += __shfl_xor(a0, 32); a1 += __shfl_xor(a1, 32);
    a2 += __shfl_xor(a2, 32); a3 += __shfl_xor(a3, 32);

    // self-loop + bias (mirrored across halves)
    float di = dinv[wid];
    float sn = di * di;
    uint2 ts = tb2[(size_t)wid * 32 + fl];
    a0 += sn * bf_lo(ts.x); a1 += sn * bf_hi(ts.x);
    a2 += sn * bf_lo(ts.y); a3 += sn * bf_hi(ts.y);
    float4 bb = ((const float4*)bias)[fl];
    a0 += bb.x; a1 += bb.y; a2 += bb.z; a3 += bb.w;

    if (PROJECT) {
        float4 wv = ((const float4*)wc2)[fl];
        float d = a0 * wv.x + a1 * wv.y + a2 * wv.z + a3 * wv.w;
        if (half) d = 0.f;                    // halves mirror: count once
#pragma unroll
        for (int off = 32; off > 0; off >>= 1) d += __shfl_xor(d, off);
        if (lane == 0) ((float*)out)[wid] = d;     // s[wid], fp32
    } else if (half == 0) {
        float4 o; o.x = a0; o.y = a1; o.z = a2; o.w = a3;
        ((float4*)out)[(size_t)wid * 32 + fl] = o; // fp32 h state
    }
}

// ---------- final: scalar gather  out[i] = sigmoid( A s + c2 ) ----------
__global__ __launch_bounds__(256) void aggFinal_kernel(const float* __restrict__ s,
                                                       const int* __restrict__ row_ptr,
                                                       const unsigned* __restrict__ edata,
                                                       const float* __restrict__ dinv,
                                                       const float* __restrict__ c2,
                                                       float* __restrict__ out, int n) {
    int wid  = (int)((blockIdx.x * (size_t)blockDim.x + threadIdx.x) >> 6);
    int lane = threadIdx.x & 63;
    if (wid >= n) return;
    int start = row_ptr[wid], end = row_ptr[wid + 1];
    float acc = 0.f;
    for (int base = start; base < end; base += 64) {
        int idx = base + lane;
        if (idx < end) {                      // pads have norm=0 -> harmless
            unsigned ed = edata[idx];
            float w = __uint_as_float((ed & 0x7fffu) << 16);
            acc += w * s[ed >> 15];
        }
    }
#pragma unroll
    for (int off = 32; off > 0; off >>= 1) acc += __shfl_xor(acc, off);
    if (lane == 0) {
        float di = dinv[wid];
        float d = acc + di * di * s[wid] + c2[0];
        out[wid] = 1.0f / (1.0f + expf(-d));
    }
}

static inline char* align16(char* p) { return (char*)(((uintptr_t)p + 15) & ~(uintptr_t)15); }

extern "C" void kernel_launch(void* const* d_in, const int* in_sizes, int n_in,
                              void* d_out, int out_size, void* d_ws, size_t ws_size,
                              hipStream_t stream) {
    const float* x  = (const float*)d_in[0];
    const int*   ei = (const int*)d_in[1];   // [2, E] int32
    const float* ea = (const float*)d_in[2]; // [E]
    const float* W1 = (const float*)d_in[3];
    const float* b1 = (const float*)d_in[4];
    const float* Wg = (const float*)d_in[5]; // [3,128,128]
    const float* bg = (const float*)d_in[6]; // [3,128]
    const float* W2 = (const float*)d_in[7]; // [128]
    const float* b2 = (const float*)d_in[8]; // [1]

    const int N = in_sizes[0] / 128;
    const int E = in_sizes[2];
    const int Npad = (N + 127) & ~127;
    const int* row = ei;
    const int* col = ei + E;

    // workspace layout
    char* p = (char*)d_ws;
    float*          hbuf = (float*)p;          p += (size_t)Npad * 128 * 4;  // fp32 h state
    unsigned short* tbuf = (unsigned short*)p; p += (size_t)Npad * 128 * 2;  // bf16 messages
    unsigned short* wbuf = (unsigned short*)p; p += 2 * 16384 * 2;           // Wt0(=Wc0^T), Wt1
    float* bc0 = (float*)p;  p += 128 * 4;
    float* wc2 = (float*)p;  p += 128 * 4;
    float* c2  = (float*)p;  p += 16;
    float* sbuf = (float*)p; p += (size_t)N * 4;
    p = align16(p);
    unsigned long long* packed = (unsigned long long*)p; p += (size_t)N * 8;
    float* dinv   = (float*)p; p += (size_t)N * 4;
    int* row_ptr  = (int*)p;   p += (size_t)(N + 1) * 4; p = align16(p);
    int* bsum     = (int*)p;   p += 256 * 4;
    unsigned short* rank = (unsigned short*)p; p += (size_t)E * 2; p = align16(p);
    unsigned* edata = (unsigned*)p;                    // E + 7N + 64 padded records

    dim3 b256(256);
    int nblk  = (N + 1023) / 1024;          // 98 (<=256)
    int nGemm = Npad / 128;                 // 782
    int nHist = (E + 1023) / 1024;          // 1563 (4 edges/thread)
    int nScat = (E + 1023) / 1024;          // 1563
    int nPrep = (max(N, 33025) + 255) / 256;

    int gridA = nHist + nGemm;
    int KA    = (gridA + nGemm - 1) / nGemm;   // 3

    prep_kernel<<<nPrep, b256, 0, stream>>>(W1, Wg, b1, W2, bg, b2,
                                            wbuf, wbuf + 16384, wc2, bc0, c2, packed, N);
    fusedA_kernel<<<gridA, b256, 0, stream>>>(col, ea, packed, rank, E,
                                              x, wbuf, bc0, tbuf, N, nGemm, KA);
    scan1_kernel<<<nblk, b256, 0, stream>>>(packed, bsum, N);
    scan3_kernel<<<nblk, b256, 0, stream>>>(packed, bsum, row_ptr, dinv, edata, N, nblk);
    scatter_kernel<<<nScat, b256, 0, stream>>>(row, col, ea, dinv, row_ptr, rank, edata, E);

    int wave_blocks = (int)(((size_t)N * 64 + 255) / 256);

    // agg0 -> hbuf(fp32); gemm(Wg1) -> tbuf; agg1+project -> sbuf; final scalar gather
    aggregate_kernel<false><<<wave_blocks, b256, 0, stream>>>(
        (const uint2*)tbuf, row_ptr, edata, dinv, bg, nullptr, hbuf, N);
    gemm_mfma_kernel<<<nGemm, b256, 0, stream>>>(hbuf, wbuf + 16384, tbuf, N);
    aggregate_kernel<true><<<wave_blocks, b256, 0, stream>>>(
        (const uint2*)tbuf, row_ptr, edata, dinv, bg + 128, wc2, sbuf, N);
    aggFinal_kernel<<<wave_blocks, b256, 0, stream>>>(sbuf, row_ptr, edata, dinv, c2,
                                                      (float*)d_out, N);
}